// Round 1
// baseline (468.724 us; speedup 1.0000x reference)
//
#include <hip/hip_runtime.h>

typedef __attribute__((ext_vector_type(8))) short short8;
typedef __attribute__((ext_vector_type(4))) float f32x4;

__device__ __forceinline__ unsigned short f2bf(float f) {
  unsigned int x = __float_as_uint(f);
  x += 0x7fffu + ((x >> 16) & 1u);
  return (unsigned short)(x >> 16);
}
__device__ __forceinline__ float bf2f(unsigned short u) {
  return __uint_as_float(((unsigned int)u) << 16);
}

// ---------------- f32 -> bf16 conversion, 4 elems/thread ----------------
__global__ void cvt_f2b(const float* __restrict__ s, unsigned short* __restrict__ d, int n) {
  int i = (blockIdx.x * 256 + threadIdx.x) * 4;
  if (i < n) {
    float4 v = *(const float4*)(s + i);
    ushort4 o;
    o.x = f2bf(v.x); o.y = f2bf(v.y); o.z = f2bf(v.z); o.w = f2bf(v.w);
    *(ushort4*)(d + i) = o;
  }
}

// ---------------- GEMM: Y[M x 1024] = X[M x 1024] @ W^T + bias ----------------
// W stored [1024(out)][1024(k)] row-major (== B^T layout).
// MODE 0: out bf16 head layout [b][16][Nn][64], Nn = 1<<nnShift
// MODE 1: out bf16 head-transposed [b][16][64][Nn]
// MODE 2: out f32 row-major [M][1024]
template<int MODE>
__global__ __launch_bounds__(256) void gemm_bt(const unsigned short* __restrict__ X,
                                               const unsigned short* __restrict__ Wt,
                                               const float* __restrict__ bias,
                                               void* __restrict__ outp, int nnShift) {
  __shared__ unsigned short As[128][72];  // +8 pad: 144B stride, 2-way conflict (free)
  __shared__ unsigned short Bs[128][72];
  const int tid = threadIdx.x;
  const int lane = tid & 63;
  const int wv = tid >> 6;
  const int wr = (wv >> 1) * 64, wc = (wv & 1) * 64;
  const int rowbase = blockIdx.x * 128, colbase = blockIdx.y * 128;
  const int rq = lane >> 4, cq = lane & 15;
  f32x4 acc[4][4] = {};
  for (int k0 = 0; k0 < 1024; k0 += 64) {
#pragma unroll
    for (int p = 0; p < 4; ++p) {
      int idx = p * 256 + tid;
      int r = idx >> 3, c8 = (idx & 7) * 8;
      *(short8*)(&As[r][c8]) = *(const short8*)(X + (size_t)(rowbase + r) * 1024 + k0 + c8);
      *(short8*)(&Bs[r][c8]) = *(const short8*)(Wt + (size_t)(colbase + r) * 1024 + k0 + c8);
    }
    __syncthreads();
#pragma unroll
    for (int kk = 0; kk < 2; ++kk) {
      const int kc = kk * 32 + rq * 8;
      short8 a[4], b[4];
#pragma unroll
      for (int m = 0; m < 4; ++m) a[m] = *(const short8*)(&As[wr + m * 16 + cq][kc]);
#pragma unroll
      for (int n = 0; n < 4; ++n) b[n] = *(const short8*)(&Bs[wc + n * 16 + cq][kc]);
#pragma unroll
      for (int m = 0; m < 4; ++m)
#pragma unroll
        for (int n = 0; n < 4; ++n)
          acc[m][n] = __builtin_amdgcn_mfma_f32_16x16x32_bf16(a[m], b[n], acc[m][n], 0, 0, 0);
    }
    __syncthreads();
  }
  // epilogue
#pragma unroll
  for (int m = 0; m < 4; ++m)
#pragma unroll
    for (int n = 0; n < 4; ++n)
#pragma unroll
      for (int r = 0; r < 4; ++r) {
        int grow = rowbase + wr + m * 16 + rq * 4 + r;
        int gcol = colbase + wc + n * 16 + cq;
        float val = acc[m][n][r] + bias[gcol];
        if (MODE == 2) {
          ((float*)outp)[(size_t)grow * 1024 + gcol] = val;
        } else {
          int bb = grow >> nnShift;
          int nr = grow & ((1 << nnShift) - 1);
          int hh = gcol >> 6, dd = gcol & 63;
          if (MODE == 0)
            ((unsigned short*)outp)[((((size_t)bb * 16 + hh) << nnShift) + nr) * 64 + dd] = f2bf(val);
          else
            ((unsigned short*)outp)[(((size_t)bb * 16 + hh) * 64 + dd) * (size_t)(1 << nnShift) + nr] = f2bf(val);
        }
      }
}

// ---------------- cross path: cross[b,h,j] = sum_w softmax_j(w1[w] . v3[j]) ----------------
// grid = bs*16 blocks, 256 threads (4 waves x 32 w-rows each). Two-pass exact softmax.
__global__ __launch_bounds__(256) void cross_kernel(const unsigned short* __restrict__ w1,
                                                    const unsigned short* __restrict__ v3,
                                                    float* __restrict__ cross) {
  __shared__ float cbuf[4][1024];
  const int tid = threadIdx.x, lane = tid & 63, wv = tid >> 6;
  const int rq = lane >> 4, cq = lane & 15;
  for (int i = tid; i < 4096; i += 256) ((float*)cbuf)[i] = 0.f;
  __syncthreads();
  const unsigned short* w1h = w1 + (size_t)blockIdx.x * 128 * 64;
  const unsigned short* v3h = v3 + (size_t)blockIdx.x * 1024 * 64;
  short8 a_w[2][2];
#pragma unroll
  for (int t = 0; t < 2; ++t)
#pragma unroll
    for (int kk = 0; kk < 2; ++kk)
      a_w[t][kk] = *(const short8*)(w1h + (size_t)(wv * 32 + t * 16 + cq) * 64 + kk * 32 + rq * 8);
  float mrow[2][4], lrow[2][4];
#pragma unroll
  for (int t = 0; t < 2; ++t)
#pragma unroll
    for (int r = 0; r < 4; ++r) { mrow[t][r] = -3e38f; lrow[t][r] = 0.f; }
  // pass 1: running max & denom
  for (int jt = 0; jt < 1024; jt += 64) {
    f32x4 s[2][4] = {};
#pragma unroll
    for (int n = 0; n < 4; ++n) {
      short8 bk[2];
#pragma unroll
      for (int kk = 0; kk < 2; ++kk)
        bk[kk] = *(const short8*)(v3h + (size_t)(jt + n * 16 + cq) * 64 + kk * 32 + rq * 8);
#pragma unroll
      for (int t = 0; t < 2; ++t)
#pragma unroll
        for (int kk = 0; kk < 2; ++kk)
          s[t][n] = __builtin_amdgcn_mfma_f32_16x16x32_bf16(a_w[t][kk], bk[kk], s[t][n], 0, 0, 0);
    }
#pragma unroll
    for (int t = 0; t < 2; ++t) {
      float tm[4], ps[4];
#pragma unroll
      for (int r = 0; r < 4; ++r)
        tm[r] = fmaxf(fmaxf(s[t][0][r], s[t][1][r]), fmaxf(s[t][2][r], s[t][3][r]));
      for (int off = 1; off < 16; off <<= 1)
#pragma unroll
        for (int r = 0; r < 4; ++r) tm[r] = fmaxf(tm[r], __shfl_xor(tm[r], off));
#pragma unroll
      for (int r = 0; r < 4; ++r) {
        float mn = fmaxf(mrow[t][r], tm[r]);
        float al = __expf(mrow[t][r] - mn);
        mrow[t][r] = mn;
        float p = 0.f;
#pragma unroll
        for (int n = 0; n < 4; ++n) p += __expf(s[t][n][r] - mn);
        ps[r] = p;
        lrow[t][r] *= al;
      }
      for (int off = 1; off < 16; off <<= 1)
#pragma unroll
        for (int r = 0; r < 4; ++r) ps[r] += __shfl_xor(ps[r], off);
#pragma unroll
      for (int r = 0; r < 4; ++r) lrow[t][r] += ps[r];
    }
  }
  float rl[2][4];
#pragma unroll
  for (int t = 0; t < 2; ++t)
#pragma unroll
    for (int r = 0; r < 4; ++r) rl[t][r] = 1.f / lrow[t][r];
  // pass 2: accumulate probabilities into per-wave column buffer
  for (int jt = 0; jt < 1024; jt += 64) {
    f32x4 s[2][4] = {};
#pragma unroll
    for (int n = 0; n < 4; ++n) {
      short8 bk[2];
#pragma unroll
      for (int kk = 0; kk < 2; ++kk)
        bk[kk] = *(const short8*)(v3h + (size_t)(jt + n * 16 + cq) * 64 + kk * 32 + rq * 8);
#pragma unroll
      for (int t = 0; t < 2; ++t)
#pragma unroll
        for (int kk = 0; kk < 2; ++kk)
          s[t][n] = __builtin_amdgcn_mfma_f32_16x16x32_bf16(a_w[t][kk], bk[kk], s[t][n], 0, 0, 0);
    }
    float colsum[4] = {0.f, 0.f, 0.f, 0.f};
#pragma unroll
    for (int t = 0; t < 2; ++t)
#pragma unroll
      for (int n = 0; n < 4; ++n)
#pragma unroll
        for (int r = 0; r < 4; ++r)
          colsum[n] += __expf(s[t][n][r] - mrow[t][r]) * rl[t][r];
#pragma unroll
    for (int n = 0; n < 4; ++n) {
      colsum[n] += __shfl_xor(colsum[n], 16);
      colsum[n] += __shfl_xor(colsum[n], 32);
    }
    if (lane < 16) {
#pragma unroll
      for (int n = 0; n < 4; ++n) cbuf[wv][jt + n * 16 + lane] += colsum[n];
    }
  }
  __syncthreads();
  for (int j = tid; j < 1024; j += 256)
    cross[(size_t)blockIdx.x * 1024 + j] = cbuf[0][j] + cbuf[1][j] + cbuf[2][j] + cbuf[3][j];
}

// ---------------- fused self-attention: softmax(v1@v2^T + cross) @ v4 ----------------
// grid = bs*16*16 (bh x i-block of 64 rows), 256 threads = 4 waves x 16 q-rows.
__global__ __launch_bounds__(256) void attn_kernel(const unsigned short* __restrict__ v1,
                                                   const unsigned short* __restrict__ v2,
                                                   const unsigned short* __restrict__ v4t,
                                                   const float* __restrict__ cross,
                                                   unsigned short* __restrict__ ctx) {
  __shared__ unsigned short Pbuf[4][16][72];
  const int bh = blockIdx.x >> 4, ib = blockIdx.x & 15;
  const int b = bh >> 4, h = bh & 15;
  const int tid = threadIdx.x, lane = tid & 63, wv = tid >> 6;
  const int rq = lane >> 4, cq = lane & 15;
  const unsigned short* v1h = v1 + (size_t)bh * 1024 * 64;
  const unsigned short* v2h = v2 + (size_t)bh * 1024 * 64;
  const unsigned short* v4h = v4t + (size_t)bh * 64 * 1024;
  const float* ch = cross + (size_t)bh * 1024;
  const int i0 = ib * 64 + wv * 16;
  short8 a_q[2];
#pragma unroll
  for (int kk = 0; kk < 2; ++kk)
    a_q[kk] = *(const short8*)(v1h + (size_t)(i0 + cq) * 64 + kk * 32 + rq * 8);
  float m[4], lsum[4];
  f32x4 o[4] = {};
#pragma unroll
  for (int r = 0; r < 4; ++r) { m[r] = -3e38f; lsum[r] = 0.f; }
  for (int jt = 0; jt < 1024; jt += 64) {
    f32x4 s[4] = {};
#pragma unroll
    for (int n = 0; n < 4; ++n) {
      short8 bk[2];
#pragma unroll
      for (int kk = 0; kk < 2; ++kk)
        bk[kk] = *(const short8*)(v2h + (size_t)(jt + n * 16 + cq) * 64 + kk * 32 + rq * 8);
#pragma unroll
      for (int kk = 0; kk < 2; ++kk)
        s[n] = __builtin_amdgcn_mfma_f32_16x16x32_bf16(a_q[kk], bk[kk], s[n], 0, 0, 0);
    }
    // add cross bias (same column j for all 4 acc rows of this lane)
#pragma unroll
    for (int n = 0; n < 4; ++n) {
      float cj = ch[jt + n * 16 + cq];
#pragma unroll
      for (int r = 0; r < 4; ++r) s[n][r] += cj;
    }
    // online softmax
    float tm[4];
#pragma unroll
    for (int r = 0; r < 4; ++r)
      tm[r] = fmaxf(fmaxf(s[0][r], s[1][r]), fmaxf(s[2][r], s[3][r]));
    for (int off = 1; off < 16; off <<= 1)
#pragma unroll
      for (int r = 0; r < 4; ++r) tm[r] = fmaxf(tm[r], __shfl_xor(tm[r], off));
    float alpha[4], ps[4];
#pragma unroll
    for (int r = 0; r < 4; ++r) {
      float mn = fmaxf(m[r], tm[r]);
      alpha[r] = __expf(m[r] - mn);
      m[r] = mn;
      ps[r] = 0.f;
    }
#pragma unroll
    for (int n = 0; n < 4; ++n)
#pragma unroll
      for (int r = 0; r < 4; ++r) {
        float p = __expf(s[n][r] - m[r]);
        s[n][r] = p;
        ps[r] += p;
      }
    for (int off = 1; off < 16; off <<= 1)
#pragma unroll
      for (int r = 0; r < 4; ++r) ps[r] += __shfl_xor(ps[r], off);
#pragma unroll
    for (int r = 0; r < 4; ++r) lsum[r] = lsum[r] * alpha[r] + ps[r];
    // P: C-layout -> LDS -> A-layout
#pragma unroll
    for (int n = 0; n < 4; ++n)
#pragma unroll
      for (int r = 0; r < 4; ++r)
        Pbuf[wv][rq * 4 + r][n * 16 + cq] = f2bf(s[n][r]);
    __syncthreads();
    short8 a_p[2];
#pragma unroll
    for (int kk = 0; kk < 2; ++kk)
      a_p[kk] = *(const short8*)(&Pbuf[wv][cq][kk * 32 + rq * 8]);
    // rescale O, then accumulate P @ V
#pragma unroll
    for (int n = 0; n < 4; ++n)
#pragma unroll
      for (int r = 0; r < 4; ++r) o[n][r] *= alpha[r];
#pragma unroll
    for (int n = 0; n < 4; ++n) {
      short8 bv[2];
#pragma unroll
      for (int kk = 0; kk < 2; ++kk)
        bv[kk] = *(const short8*)(v4h + (size_t)(n * 16 + cq) * 1024 + jt + kk * 32 + rq * 8);
#pragma unroll
      for (int kk = 0; kk < 2; ++kk)
        o[n] = __builtin_amdgcn_mfma_f32_16x16x32_bf16(a_p[kk], bv[kk], o[n], 0, 0, 0);
    }
    __syncthreads();
  }
  float rinv[4];
#pragma unroll
  for (int r = 0; r < 4; ++r) rinv[r] = 1.f / lsum[r];
#pragma unroll
  for (int n = 0; n < 4; ++n)
#pragma unroll
    for (int r = 0; r < 4; ++r) {
      float val = o[n][r] * rinv[r];
      int row = i0 + rq * 4 + r;
      int col = h * 64 + n * 16 + cq;
      ctx[((size_t)b * 1024 + row) * 1024 + col] = f2bf(val);
    }
}

extern "C" void kernel_launch(void* const* d_in, const int* in_sizes, int n_in,
                              void* d_out, int out_size, void* d_ws, size_t ws_size,
                              hipStream_t stream) {
  const int bs = in_sizes[0] / (128 * 1024);  // = 4
  char* w = (char*)d_ws;
  size_t off = 0;
  auto alloc = [&](size_t bytes) -> void* {
    void* p = w + off;
    off += (bytes + 255) & ~(size_t)255;
    return p;
  };
  unsigned short* wfeat_b = (unsigned short*)alloc((size_t)bs * 128 * 1024 * 2);
  unsigned short* vfeat_b = (unsigned short*)alloc((size_t)bs * 1024 * 1024 * 2);
  unsigned short* Ww1b = (unsigned short*)alloc((size_t)1024 * 1024 * 2);
  unsigned short* Wv1b = (unsigned short*)alloc((size_t)1024 * 1024 * 2);
  unsigned short* Wv2b = (unsigned short*)alloc((size_t)1024 * 1024 * 2);
  unsigned short* Wv3b = (unsigned short*)alloc((size_t)1024 * 1024 * 2);
  unsigned short* Wv4b = (unsigned short*)alloc((size_t)1024 * 1024 * 2);
  unsigned short* Woutb = (unsigned short*)alloc((size_t)1024 * 1024 * 2);
  unsigned short* w1b = (unsigned short*)alloc((size_t)bs * 16 * 128 * 64 * 2);
  unsigned short* v1b = (unsigned short*)alloc((size_t)bs * 16 * 1024 * 64 * 2);
  unsigned short* v2b = (unsigned short*)alloc((size_t)bs * 16 * 1024 * 64 * 2);
  unsigned short* v3b = (unsigned short*)alloc((size_t)bs * 16 * 1024 * 64 * 2);
  unsigned short* v4tb = (unsigned short*)alloc((size_t)bs * 16 * 64 * 1024 * 2);
  unsigned short* ctxb = (unsigned short*)alloc((size_t)bs * 1024 * 1024 * 2);
  float* crossb = (float*)alloc((size_t)bs * 16 * 1024 * 4);

  auto cvt = [&](const void* src, unsigned short* dst, int n) {
    cvt_f2b<<<(n / 4 + 255) / 256, 256, 0, stream>>>((const float*)src, dst, n);
  };
  cvt(d_in[0], wfeat_b, bs * 128 * 1024);
  cvt(d_in[1], vfeat_b, bs * 1024 * 1024);
  cvt(d_in[2], Ww1b, 1024 * 1024);
  cvt(d_in[4], Wv1b, 1024 * 1024);
  cvt(d_in[6], Wv2b, 1024 * 1024);
  cvt(d_in[8], Wv3b, 1024 * 1024);
  cvt(d_in[10], Wv4b, 1024 * 1024);
  cvt(d_in[12], Woutb, 1024 * 1024);

  dim3 blk(256);
  // projections
  gemm_bt<0><<<dim3(bs * 128 / 128, 8), blk, 0, stream>>>(wfeat_b, Ww1b, (const float*)d_in[3], w1b, 7);
  gemm_bt<0><<<dim3(bs * 1024 / 128, 8), blk, 0, stream>>>(vfeat_b, Wv1b, (const float*)d_in[5], v1b, 10);
  gemm_bt<0><<<dim3(bs * 1024 / 128, 8), blk, 0, stream>>>(vfeat_b, Wv2b, (const float*)d_in[7], v2b, 10);
  gemm_bt<0><<<dim3(bs * 1024 / 128, 8), blk, 0, stream>>>(vfeat_b, Wv3b, (const float*)d_in[9], v3b, 10);
  gemm_bt<1><<<dim3(bs * 1024 / 128, 8), blk, 0, stream>>>(vfeat_b, Wv4b, (const float*)d_in[11], v4tb, 10);
  // cross bias
  cross_kernel<<<bs * 16, blk, 0, stream>>>(w1b, v3b, crossb);
  // fused attention
  attn_kernel<<<bs * 16 * 16, blk, 0, stream>>>(v1b, v2b, v4tb, crossb, ctxb);
  // output projection (f32 out + bias)
  gemm_bt<2><<<dim3(bs * 1024 / 128, 8), blk, 0, stream>>>(ctxb, Woutb, (const float*)d_in[13], (float*)d_out, 0);
}

// Round 3
// 456.298 us; speedup vs baseline: 1.0272x; 1.0272x over previous
//
#include <hip/hip_runtime.h>

typedef __attribute__((ext_vector_type(8))) short short8;
typedef __attribute__((ext_vector_type(4))) float f32x4;

__device__ __forceinline__ unsigned short f2bf(float f) {
  unsigned int x = __float_as_uint(f);
  x += 0x7fffu + ((x >> 16) & 1u);
  return (unsigned short)(x >> 16);
}

__device__ __forceinline__ void gload_lds16(const void* g, void* l) {
  __builtin_amdgcn_global_load_lds((const __attribute__((address_space(1))) unsigned int*)g,
                                   (__attribute__((address_space(3))) unsigned int*)l, 16, 0, 0);
}

// ---------------- f32 -> bf16 conversion, 4 elems/thread ----------------
__global__ void cvt_f2b(const float* __restrict__ s, unsigned short* __restrict__ d, int n) {
  int i = (blockIdx.x * 256 + threadIdx.x) * 4;
  if (i < n) {
    float4 v = *(const float4*)(s + i);
    ushort4 o;
    o.x = f2bf(v.x); o.y = f2bf(v.y); o.z = f2bf(v.z); o.w = f2bf(v.w);
    *(ushort4*)(d + i) = o;
  }
}

// ---------------- GEMM (m97 structure): Y[M x 1024] = X[M x 1024] @ W^T + bias ----------------
// Linear LDS [128][64] bf16, staged via global_load_lds width=16.
// MODE 0: out bf16 head layout [b][16][Nn][64]; MODE 1: bf16 [b][16][64][Nn]; MODE 2: f32 [M][1024]
template<int MODE>
__global__ __launch_bounds__(256) void gemm_bt(const unsigned short* __restrict__ X,
                                               const unsigned short* __restrict__ Wt,
                                               const float* __restrict__ bias,
                                               void* __restrict__ outp, int nnShift) {
  __shared__ unsigned short As[128][64];
  __shared__ unsigned short Bs[128][64];
  const int tid = threadIdx.x;
  const int lane = tid & 63;
  const int wv = tid >> 6;
  const int wr = (wv >> 1) * 64, wc = (wv & 1) * 64;
  const int rowbase = blockIdx.x * 128, colbase = blockIdx.y * 128;
  const int rq = lane >> 4, cq = lane & 15;
  // staging geometry: call c of wave wv covers LDS rows [(wv*4+c)*8, +8), lane -> row +lane/8, 16B chunk lane%8
  const int srow = wv * 32 + (lane >> 3);
  const int schunk = (lane & 7) * 8;
  f32x4 acc[4][4] = {};
  for (int k0 = 0; k0 < 1024; k0 += 64) {
#pragma unroll
    for (int c = 0; c < 4; ++c) {
      int r = srow + c * 8;
      gload_lds16(X + (size_t)(rowbase + r) * 1024 + k0 + schunk, &As[wv * 32 + c * 8][0]);
      gload_lds16(Wt + (size_t)(colbase + r) * 1024 + k0 + schunk, &Bs[wv * 32 + c * 8][0]);
    }
    __syncthreads();
#pragma unroll
    for (int kk = 0; kk < 2; ++kk) {
      const int kc = kk * 32 + rq * 8;
      short8 a[4], b[4];
#pragma unroll
      for (int m = 0; m < 4; ++m) a[m] = *(const short8*)(&As[wr + m * 16 + cq][kc]);
#pragma unroll
      for (int n = 0; n < 4; ++n) b[n] = *(const short8*)(&Bs[wc + n * 16 + cq][kc]);
#pragma unroll
      for (int m = 0; m < 4; ++m)
#pragma unroll
        for (int n = 0; n < 4; ++n)
          acc[m][n] = __builtin_amdgcn_mfma_f32_16x16x32_bf16(a[m], b[n], acc[m][n], 0, 0, 0);
    }
    __syncthreads();
  }
  // epilogue
#pragma unroll
  for (int m = 0; m < 4; ++m)
#pragma unroll
    for (int n = 0; n < 4; ++n)
#pragma unroll
      for (int r = 0; r < 4; ++r) {
        int grow = rowbase + wr + m * 16 + rq * 4 + r;
        int gcol = colbase + wc + n * 16 + cq;
        float val = acc[m][n][r] + bias[gcol];
        if (MODE == 2) {
          ((float*)outp)[(size_t)grow * 1024 + gcol] = val;
        } else {
          int bb = grow >> nnShift;
          int nr = grow & ((1 << nnShift) - 1);
          int hh = gcol >> 6, dd = gcol & 63;
          if (MODE == 0)
            ((unsigned short*)outp)[((((size_t)bb * 16 + hh) << nnShift) + nr) * 64 + dd] = f2bf(val);
          else
            ((unsigned short*)outp)[(((size_t)bb * 16 + hh) * 64 + dd) * (size_t)(1 << nnShift) + nr] = f2bf(val);
        }
      }
}

// ---------------- cross path: cross[b,h,j] = sum_w softmax_j(w1[w] . v3[j]) ----------------
__global__ __launch_bounds__(256) void cross_kernel(const unsigned short* __restrict__ w1,
                                                    const unsigned short* __restrict__ v3,
                                                    float* __restrict__ cross) {
  __shared__ float cbuf[4][1024];
  const int tid = threadIdx.x, lane = tid & 63, wv = tid >> 6;
  const int rq = lane >> 4, cq = lane & 15;
  for (int i = tid; i < 4096; i += 256) ((float*)cbuf)[i] = 0.f;
  __syncthreads();
  const unsigned short* w1h = w1 + (size_t)blockIdx.x * 128 * 64;
  const unsigned short* v3h = v3 + (size_t)blockIdx.x * 1024 * 64;
  short8 a_w[2][2];
#pragma unroll
  for (int t = 0; t < 2; ++t)
#pragma unroll
    for (int kk = 0; kk < 2; ++kk)
      a_w[t][kk] = *(const short8*)(w1h + (size_t)(wv * 32 + t * 16 + cq) * 64 + kk * 32 + rq * 8);
  float mrow[2][4], lrow[2][4];
#pragma unroll
  for (int t = 0; t < 2; ++t)
#pragma unroll
    for (int r = 0; r < 4; ++r) { mrow[t][r] = -3e38f; lrow[t][r] = 0.f; }
  for (int jt = 0; jt < 1024; jt += 64) {
    f32x4 s[2][4] = {};
#pragma unroll
    for (int n = 0; n < 4; ++n) {
      short8 bk[2];
#pragma unroll
      for (int kk = 0; kk < 2; ++kk)
        bk[kk] = *(const short8*)(v3h + (size_t)(jt + n * 16 + cq) * 64 + kk * 32 + rq * 8);
#pragma unroll
      for (int t = 0; t < 2; ++t)
#pragma unroll
        for (int kk = 0; kk < 2; ++kk)
          s[t][n] = __builtin_amdgcn_mfma_f32_16x16x32_bf16(a_w[t][kk], bk[kk], s[t][n], 0, 0, 0);
    }
#pragma unroll
    for (int t = 0; t < 2; ++t) {
      float tm[4], ps[4];
#pragma unroll
      for (int r = 0; r < 4; ++r)
        tm[r] = fmaxf(fmaxf(s[t][0][r], s[t][1][r]), fmaxf(s[t][2][r], s[t][3][r]));
      for (int off = 1; off < 16; off <<= 1)
#pragma unroll
        for (int r = 0; r < 4; ++r) tm[r] = fmaxf(tm[r], __shfl_xor(tm[r], off));
#pragma unroll
      for (int r = 0; r < 4; ++r) {
        float mn = fmaxf(mrow[t][r], tm[r]);
        float al = __expf(mrow[t][r] - mn);
        mrow[t][r] = mn;
        float p = 0.f;
#pragma unroll
        for (int n = 0; n < 4; ++n) p += __expf(s[t][n][r] - mn);
        ps[r] = p;
        lrow[t][r] *= al;
      }
      for (int off = 1; off < 16; off <<= 1)
#pragma unroll
        for (int r = 0; r < 4; ++r) ps[r] += __shfl_xor(ps[r], off);
#pragma unroll
      for (int r = 0; r < 4; ++r) lrow[t][r] += ps[r];
    }
  }
  float rl[2][4];
#pragma unroll
  for (int t = 0; t < 2; ++t)
#pragma unroll
    for (int r = 0; r < 4; ++r) rl[t][r] = 1.f / lrow[t][r];
  for (int jt = 0; jt < 1024; jt += 64) {
    f32x4 s[2][4] = {};
#pragma unroll
    for (int n = 0; n < 4; ++n) {
      short8 bk[2];
#pragma unroll
      for (int kk = 0; kk < 2; ++kk)
        bk[kk] = *(const short8*)(v3h + (size_t)(jt + n * 16 + cq) * 64 + kk * 32 + rq * 8);
#pragma unroll
      for (int t = 0; t < 2; ++t)
#pragma unroll
        for (int kk = 0; kk < 2; ++kk)
          s[t][n] = __builtin_amdgcn_mfma_f32_16x16x32_bf16(a_w[t][kk], bk[kk], s[t][n], 0, 0, 0);
    }
    float colsum[4] = {0.f, 0.f, 0.f, 0.f};
#pragma unroll
    for (int t = 0; t < 2; ++t)
#pragma unroll
      for (int n = 0; n < 4; ++n)
#pragma unroll
        for (int r = 0; r < 4; ++r)
          colsum[n] += __expf(s[t][n][r] - mrow[t][r]) * rl[t][r];
#pragma unroll
    for (int n = 0; n < 4; ++n) {
      colsum[n] += __shfl_xor(colsum[n], 16);
      colsum[n] += __shfl_xor(colsum[n], 32);
    }
    if (lane < 16) {
#pragma unroll
      for (int n = 0; n < 4; ++n) cbuf[wv][jt + n * 16 + lane] += colsum[n];
    }
  }
  __syncthreads();
  for (int j = tid; j < 1024; j += 256)
    cross[(size_t)blockIdx.x * 1024 + j] = cbuf[0][j] + cbuf[1][j] + cbuf[2][j] + cbuf[3][j];
}

// ---------------- fused self-attention, swapped-QK, barrier-free ----------------
// grid = bs*16*16 (bh x i-block of 64 rows), 256 threads = 4 waves x 16 q-rows each.
// QK computed as mfma(K_frag, Q_frag): lane holds s[j = jt+mp*16+rq*4+r][q = cq].
// Row-softmax = in-lane 16-reg reduce + 2 shfl_xor stages. P -> LDS (per-wave slice,
// no barriers) -> A-fragment for PV.
__global__ __launch_bounds__(256) void attn_kernel(const unsigned short* __restrict__ v1,
                                                   const unsigned short* __restrict__ v2,
                                                   const unsigned short* __restrict__ v4t,
                                                   const float* __restrict__ cross,
                                                   unsigned short* __restrict__ ctx) {
  __shared__ unsigned short Pbuf[4][16][72];
  const int bh = blockIdx.x >> 4, ib = blockIdx.x & 15;
  const int b = bh >> 4, h = bh & 15;
  const int tid = threadIdx.x, lane = tid & 63, wv = tid >> 6;
  const int rq = lane >> 4, cq = lane & 15;
  const unsigned short* v1h = v1 + (size_t)bh * 1024 * 64;
  const unsigned short* v2h = v2 + (size_t)bh * 1024 * 64;
  const unsigned short* v4h = v4t + (size_t)bh * 64 * 1024;
  const float* ch = cross + (size_t)bh * 1024;
  const int i0 = ib * 64 + wv * 16;
  // Q as B-fragment: lane holds v1 row i0+cq, k-chunk rq*8
  short8 b_q[2];
#pragma unroll
  for (int kk = 0; kk < 2; ++kk)
    b_q[kk] = *(const short8*)(v1h + (size_t)(i0 + cq) * 64 + kk * 32 + rq * 8);
  float m = -3e38f, lsum = 0.f;
  f32x4 o[4] = {};
  for (int jt = 0; jt < 1024; jt += 64) {
    // QK^T swapped: s[mp] rows = keys, cols = queries
    f32x4 s[4] = {};
#pragma unroll
    for (int mp = 0; mp < 4; ++mp) {
      short8 ak[2];
#pragma unroll
      for (int kk = 0; kk < 2; ++kk)
        ak[kk] = *(const short8*)(v2h + (size_t)(jt + mp * 16 + cq) * 64 + kk * 32 + rq * 8);
#pragma unroll
      for (int kk = 0; kk < 2; ++kk)
        s[mp] = __builtin_amdgcn_mfma_f32_16x16x32_bf16(ak[kk], b_q[kk], s[mp], 0, 0, 0);
    }
    // prefetch V fragments (independent of softmax chain)
    short8 bv[4][2];
#pragma unroll
    for (int n = 0; n < 4; ++n)
#pragma unroll
      for (int kk = 0; kk < 2; ++kk)
        bv[n][kk] = *(const short8*)(v4h + (size_t)(n * 16 + cq) * 1024 + jt + kk * 32 + rq * 8);
    // cross bias: j = jt + mp*16 + rq*4 + r
#pragma unroll
    for (int mp = 0; mp < 4; ++mp) {
      float4 cj = *(const float4*)(ch + jt + mp * 16 + rq * 4);
      s[mp][0] += cj.x; s[mp][1] += cj.y; s[mp][2] += cj.z; s[mp][3] += cj.w;
    }
    // online softmax for column q = cq: in-lane reduce over 16 regs + 2 shfl stages
    float tm = s[0][0];
#pragma unroll
    for (int mp = 0; mp < 4; ++mp)
#pragma unroll
      for (int r = 0; r < 4; ++r) tm = fmaxf(tm, s[mp][r]);
    tm = fmaxf(tm, __shfl_xor(tm, 16));
    tm = fmaxf(tm, __shfl_xor(tm, 32));
    float mn = fmaxf(m, tm);
    float alpha = __expf(m - mn);
    m = mn;
    float ps = 0.f;
#pragma unroll
    for (int mp = 0; mp < 4; ++mp)
#pragma unroll
      for (int r = 0; r < 4; ++r) {
        float p = __expf(s[mp][r] - mn);
        s[mp][r] = p;
        ps += p;
      }
    ps += __shfl_xor(ps, 16);
    ps += __shfl_xor(ps, 32);
    lsum = lsum * alpha + ps;
    // P -> per-wave LDS slice: Pbuf[wv][q=cq][j-local], 8B packed writes (2-way = free)
#pragma unroll
    for (int mp = 0; mp < 4; ++mp) {
      ushort4 pw;
      pw.x = f2bf(s[mp][0]); pw.y = f2bf(s[mp][1]);
      pw.z = f2bf(s[mp][2]); pw.w = f2bf(s[mp][3]);
      *(ushort4*)(&Pbuf[wv][cq][mp * 16 + rq * 4]) = pw;
    }
    // P as A-fragment: lane holds P row q=cq, j-chunk kk*32+rq*8 (wave-local LDS, in-order)
    short8 a_p[2];
#pragma unroll
    for (int kk = 0; kk < 2; ++kk)
      a_p[kk] = *(const short8*)(&Pbuf[wv][cq][kk * 32 + rq * 8]);
    // rescale O: alpha indexed by q=cq -> broadcast to q=rq*4+r
    float al[4];
#pragma unroll
    for (int r = 0; r < 4; ++r) al[r] = __shfl(alpha, rq * 4 + r);
#pragma unroll
    for (int n = 0; n < 4; ++n)
#pragma unroll
      for (int r = 0; r < 4; ++r) o[n][r] *= al[r];
#pragma unroll
    for (int n = 0; n < 4; ++n)
#pragma unroll
      for (int kk = 0; kk < 2; ++kk)
        o[n] = __builtin_amdgcn_mfma_f32_16x16x32_bf16(a_p[kk], bv[n][kk], o[n], 0, 0, 0);
  }
  float li[4];
#pragma unroll
  for (int r = 0; r < 4; ++r) li[r] = __shfl(lsum, rq * 4 + r);
#pragma unroll
  for (int n = 0; n < 4; ++n)
#pragma unroll
    for (int r = 0; r < 4; ++r) {
      float val = o[n][r] / li[r];
      int row = i0 + rq * 4 + r;
      int col = h * 64 + n * 16 + cq;
      ctx[((size_t)b * 1024 + row) * 1024 + col] = f2bf(val);
    }
}

extern "C" void kernel_launch(void* const* d_in, const int* in_sizes, int n_in,
                              void* d_out, int out_size, void* d_ws, size_t ws_size,
                              hipStream_t stream) {
  const int bs = in_sizes[0] / (128 * 1024);  // = 4
  char* w = (char*)d_ws;
  size_t off = 0;
  auto alloc = [&](size_t bytes) -> void* {
    void* p = w + off;
    off += (bytes + 255) & ~(size_t)255;
    return p;
  };
  unsigned short* wfeat_b = (unsigned short*)alloc((size_t)bs * 128 * 1024 * 2);
  unsigned short* vfeat_b = (unsigned short*)alloc((size_t)bs * 1024 * 1024 * 2);
  unsigned short* Ww1b = (unsigned short*)alloc((size_t)1024 * 1024 * 2);
  unsigned short* Wv1b = (unsigned short*)alloc((size_t)1024 * 1024 * 2);
  unsigned short* Wv2b = (unsigned short*)alloc((size_t)1024 * 1024 * 2);
  unsigned short* Wv3b = (unsigned short*)alloc((size_t)1024 * 1024 * 2);
  unsigned short* Wv4b = (unsigned short*)alloc((size_t)1024 * 1024 * 2);
  unsigned short* Woutb = (unsigned short*)alloc((size_t)1024 * 1024 * 2);
  unsigned short* w1b = (unsigned short*)alloc((size_t)bs * 16 * 128 * 64 * 2);
  unsigned short* v1b = (unsigned short*)alloc((size_t)bs * 16 * 1024 * 64 * 2);
  unsigned short* v2b = (unsigned short*)alloc((size_t)bs * 16 * 1024 * 64 * 2);
  unsigned short* v3b = (unsigned short*)alloc((size_t)bs * 16 * 1024 * 64 * 2);
  unsigned short* v4tb = (unsigned short*)alloc((size_t)bs * 16 * 64 * 1024 * 2);
  unsigned short* ctxb = (unsigned short*)alloc((size_t)bs * 1024 * 1024 * 2);
  float* crossb = (float*)alloc((size_t)bs * 16 * 1024 * 4);

  auto cvt = [&](const void* src, unsigned short* dst, int n) {
    cvt_f2b<<<(n / 4 + 255) / 256, 256, 0, stream>>>((const float*)src, dst, n);
  };
  cvt(d_in[0], wfeat_b, bs * 128 * 1024);
  cvt(d_in[1], vfeat_b, bs * 1024 * 1024);
  cvt(d_in[2], Ww1b, 1024 * 1024);
  cvt(d_in[4], Wv1b, 1024 * 1024);
  cvt(d_in[6], Wv2b, 1024 * 1024);
  cvt(d_in[8], Wv3b, 1024 * 1024);
  cvt(d_in[10], Wv4b, 1024 * 1024);
  cvt(d_in[12], Woutb, 1024 * 1024);

  dim3 blk(256);
  gemm_bt<0><<<dim3(bs * 128 / 128, 8), blk, 0, stream>>>(wfeat_b, Ww1b, (const float*)d_in[3], w1b, 7);
  gemm_bt<0><<<dim3(bs * 1024 / 128, 8), blk, 0, stream>>>(vfeat_b, Wv1b, (const float*)d_in[5], v1b, 10);
  gemm_bt<0><<<dim3(bs * 1024 / 128, 8), blk, 0, stream>>>(vfeat_b, Wv2b, (const float*)d_in[7], v2b, 10);
  gemm_bt<0><<<dim3(bs * 1024 / 128, 8), blk, 0, stream>>>(vfeat_b, Wv3b, (const float*)d_in[9], v3b, 10);
  gemm_bt<1><<<dim3(bs * 1024 / 128, 8), blk, 0, stream>>>(vfeat_b, Wv4b, (const float*)d_in[11], v4tb, 10);
  cross_kernel<<<bs * 16, blk, 0, stream>>>(w1b, v3b, crossb);
  attn_kernel<<<bs * 16 * 16, blk, 0, stream>>>(v1b, v2b, v4tb, crossb, ctxb);
  gemm_bt<2><<<dim3(bs * 1024 / 128, 8), blk, 0, stream>>>(ctxb, Woutb, (const float*)d_in[13], (float*)d_out, 0);
}

// Round 4
// 321.864 us; speedup vs baseline: 1.4563x; 1.4177x over previous
//
#include <hip/hip_runtime.h>

typedef __attribute__((ext_vector_type(8))) short short8;
typedef __attribute__((ext_vector_type(4))) float f32x4;

__device__ __forceinline__ unsigned short f2bf(float f) {
  unsigned int x = __float_as_uint(f);
  x += 0x7fffu + ((x >> 16) & 1u);
  return (unsigned short)(x >> 16);
}

__device__ __forceinline__ void gload_lds16(const void* g, void* l) {
  __builtin_amdgcn_global_load_lds((const __attribute__((address_space(1))) unsigned int*)g,
                                   (__attribute__((address_space(3))) unsigned int*)l, 16, 0, 0);
}

// ---------------- f32 -> bf16 conversion ----------------
__global__ void cvt_f2b(const float* __restrict__ s, unsigned short* __restrict__ d, int n) {
  int i = (blockIdx.x * 256 + threadIdx.x) * 4;
  if (i < n) {
    float4 v = *(const float4*)(s + i);
    ushort4 o;
    o.x = f2bf(v.x); o.y = f2bf(v.y); o.z = f2bf(v.z); o.w = f2bf(v.w);
    *(ushort4*)(d + i) = o;
  }
}

// gather 4 bias vectors into one 4096-float buffer
__global__ void gather_bias(const float* __restrict__ b0, const float* __restrict__ b1,
                            const float* __restrict__ b2, const float* __restrict__ b3,
                            float* __restrict__ out) {
  int i = blockIdx.x * 256 + threadIdx.x;  // 4096 total
  const float* src = (i < 1024) ? b0 : (i < 2048) ? b1 : (i < 3072) ? b2 : b3;
  out[i] = src[i & 1023];
}

__global__ void zero_f32(float* __restrict__ p, int n4) {
  int i = blockIdx.x * 256 + threadIdx.x;
  if (i < n4) *(float4*)(p + i * 4) = float4{0.f, 0.f, 0.f, 0.f};
}

// ---------------- GEMM (m97 structure): Y[M x 1024-or-4096] = X[M x 1024] @ W^T + bias ----------------
// MODE 0: bf16 head layout [b][16][Nn][64]; MODE 2: f32 [M][1024];
// MODE 3: fused v-proj, N=4096: col slab 0-2 -> head layout [b][16][1024][64] to o0..o2,
//         slab 3 -> transposed [b][16][64][1024] to o3. Slab uniform per block.
template<int MODE>
__global__ __launch_bounds__(256) void gemm_bt(const unsigned short* __restrict__ X,
                                               const unsigned short* __restrict__ Wt,
                                               const float* __restrict__ bias,
                                               void* __restrict__ o0, void* __restrict__ o1,
                                               void* __restrict__ o2, void* __restrict__ o3,
                                               int nnShift) {
  __shared__ unsigned short As[128][64];
  __shared__ unsigned short Bs[128][64];
  const int tid = threadIdx.x;
  const int lane = tid & 63;
  const int wv = tid >> 6;
  const int wr = (wv >> 1) * 64, wc = (wv & 1) * 64;
  const int rowbase = blockIdx.x * 128, colbase = blockIdx.y * 128;
  const int rq = lane >> 4, cq = lane & 15;
  const int srow = wv * 32 + (lane >> 3);
  const int schunk = (lane & 7) * 8;
  f32x4 acc[4][4] = {};
  for (int k0 = 0; k0 < 1024; k0 += 64) {
#pragma unroll
    for (int c = 0; c < 4; ++c) {
      int r = srow + c * 8;
      gload_lds16(X + (size_t)(rowbase + r) * 1024 + k0 + schunk, &As[wv * 32 + c * 8][0]);
      gload_lds16(Wt + (size_t)(colbase + r) * 1024 + k0 + schunk, &Bs[wv * 32 + c * 8][0]);
    }
    __syncthreads();
#pragma unroll
    for (int kk = 0; kk < 2; ++kk) {
      const int kc = kk * 32 + rq * 8;
      short8 a[4], b[4];
#pragma unroll
      for (int m = 0; m < 4; ++m) a[m] = *(const short8*)(&As[wr + m * 16 + cq][kc]);
#pragma unroll
      for (int n = 0; n < 4; ++n) b[n] = *(const short8*)(&Bs[wc + n * 16 + cq][kc]);
#pragma unroll
      for (int m = 0; m < 4; ++m)
#pragma unroll
        for (int n = 0; n < 4; ++n)
          acc[m][n] = __builtin_amdgcn_mfma_f32_16x16x32_bf16(a[m], b[n], acc[m][n], 0, 0, 0);
    }
    __syncthreads();
  }
#pragma unroll
  for (int m = 0; m < 4; ++m)
#pragma unroll
    for (int n = 0; n < 4; ++n)
#pragma unroll
      for (int r = 0; r < 4; ++r) {
        int grow = rowbase + wr + m * 16 + rq * 4 + r;
        int gcol = colbase + wc + n * 16 + cq;
        float val = acc[m][n][r] + bias[gcol];
        if (MODE == 2) {
          ((float*)o0)[(size_t)grow * 1024 + gcol] = val;
        } else if (MODE == 0) {
          int bb = grow >> nnShift;
          int nr = grow & ((1 << nnShift) - 1);
          int hh = gcol >> 6, dd = gcol & 63;
          ((unsigned short*)o0)[((((size_t)bb * 16 + hh) << nnShift) + nr) * 64 + dd] = f2bf(val);
        } else {  // MODE 3: fused v-proj, nn = 1024
          int which = gcol >> 10;  // uniform per block
          int lcol = gcol & 1023;
          int bb = grow >> 10, nr = grow & 1023;
          int hh = lcol >> 6, dd = lcol & 63;
          void* op = (which == 0) ? o0 : (which == 1) ? o1 : (which == 2) ? o2 : o3;
          if (which < 3)
            ((unsigned short*)op)[((((size_t)bb * 16 + hh) << 10) + nr) * 64 + dd] = f2bf(val);
          else
            ((unsigned short*)op)[(((size_t)bb * 16 + hh) * 64 + dd) * 1024 + nr] = f2bf(val);
        }
      }
}

// ---------------- cross path: cross[b,h,j] += sum_{w in half} softmax_j(w1[w] . v3[j]) ----------------
// grid = bs*16*2 blocks (bh x w-half of 64 rows), 4 waves x 16 w-rows. Two-pass exact softmax.
__global__ __launch_bounds__(256) void cross_kernel(const unsigned short* __restrict__ w1,
                                                    const unsigned short* __restrict__ v3,
                                                    float* __restrict__ cross) {
  __shared__ float cbuf[4][1024];
  const int tid = threadIdx.x, lane = tid & 63, wv = tid >> 6;
  const int rq = lane >> 4, cq = lane & 15;
  for (int i = tid; i < 4096; i += 256) ((float*)cbuf)[i] = 0.f;
  __syncthreads();
  const int bh = blockIdx.x >> 1, half = blockIdx.x & 1;
  const unsigned short* w1h = w1 + (size_t)bh * 128 * 64;
  const unsigned short* v3h = v3 + (size_t)bh * 1024 * 64;
  const int w0 = half * 64 + wv * 16;
  short8 a_w[2];
#pragma unroll
  for (int kk = 0; kk < 2; ++kk)
    a_w[kk] = *(const short8*)(w1h + (size_t)(w0 + cq) * 64 + kk * 32 + rq * 8);
  float mrow[4], lrow[4];
#pragma unroll
  for (int r = 0; r < 4; ++r) { mrow[r] = -3e38f; lrow[r] = 0.f; }
  for (int jt = 0; jt < 1024; jt += 64) {
    f32x4 s[4] = {};
#pragma unroll
    for (int n = 0; n < 4; ++n) {
      short8 bk[2];
#pragma unroll
      for (int kk = 0; kk < 2; ++kk)
        bk[kk] = *(const short8*)(v3h + (size_t)(jt + n * 16 + cq) * 64 + kk * 32 + rq * 8);
#pragma unroll
      for (int kk = 0; kk < 2; ++kk)
        s[n] = __builtin_amdgcn_mfma_f32_16x16x32_bf16(a_w[kk], bk[kk], s[n], 0, 0, 0);
    }
    float tm[4], ps[4];
#pragma unroll
    for (int r = 0; r < 4; ++r)
      tm[r] = fmaxf(fmaxf(s[0][r], s[1][r]), fmaxf(s[2][r], s[3][r]));
    for (int off = 1; off < 16; off <<= 1)
#pragma unroll
      for (int r = 0; r < 4; ++r) tm[r] = fmaxf(tm[r], __shfl_xor(tm[r], off));
#pragma unroll
    for (int r = 0; r < 4; ++r) {
      float mn = fmaxf(mrow[r], tm[r]);
      float al = __expf(mrow[r] - mn);
      mrow[r] = mn;
      float p = 0.f;
#pragma unroll
      for (int n = 0; n < 4; ++n) p += __expf(s[n][r] - mn);
      ps[r] = p;
      lrow[r] *= al;
    }
    for (int off = 1; off < 16; off <<= 1)
#pragma unroll
      for (int r = 0; r < 4; ++r) ps[r] += __shfl_xor(ps[r], off);
#pragma unroll
    for (int r = 0; r < 4; ++r) lrow[r] += ps[r];
  }
  float rl[4];
#pragma unroll
  for (int r = 0; r < 4; ++r) rl[r] = 1.f / lrow[r];
  for (int jt = 0; jt < 1024; jt += 64) {
    f32x4 s[4] = {};
#pragma unroll
    for (int n = 0; n < 4; ++n) {
      short8 bk[2];
#pragma unroll
      for (int kk = 0; kk < 2; ++kk)
        bk[kk] = *(const short8*)(v3h + (size_t)(jt + n * 16 + cq) * 64 + kk * 32 + rq * 8);
#pragma unroll
      for (int kk = 0; kk < 2; ++kk)
        s[n] = __builtin_amdgcn_mfma_f32_16x16x32_bf16(a_w[kk], bk[kk], s[n], 0, 0, 0);
    }
    float colsum[4] = {0.f, 0.f, 0.f, 0.f};
#pragma unroll
    for (int n = 0; n < 4; ++n)
#pragma unroll
      for (int r = 0; r < 4; ++r)
        colsum[n] += __expf(s[n][r] - mrow[r]) * rl[r];
#pragma unroll
    for (int n = 0; n < 4; ++n) {
      colsum[n] += __shfl_xor(colsum[n], 16);
      colsum[n] += __shfl_xor(colsum[n], 32);
    }
    if (lane < 16) {
#pragma unroll
      for (int n = 0; n < 4; ++n) cbuf[wv][jt + n * 16 + lane] += colsum[n];
    }
  }
  __syncthreads();
  for (int j = tid; j < 1024; j += 256)
    atomicAdd(&cross[(size_t)bh * 1024 + j], cbuf[0][j] + cbuf[1][j] + cbuf[2][j] + cbuf[3][j]);
}

// ---------------- fused self-attention, LDS-staged K/V, double-buffered ----------------
// grid = 1024 (XCD-chunk-swizzled: 128 consecutive logical blocks per XCD so the 16
// i-blocks sharing one head's 256KB K/V hit one 4MB L2). 4 waves x 16 q-rows.
// K-tile [64 j][64 k] and V^T-tile [64 d][64 j] staged per block via global_load_lds
// (linear LDS dest + inverse-swizzled global source; reads XOR-swizzle chunk ^= row&7).
__global__ __launch_bounds__(256) void attn_kernel(const unsigned short* __restrict__ v1,
                                                   const unsigned short* __restrict__ v2,
                                                   const unsigned short* __restrict__ v4t,
                                                   const float* __restrict__ cross,
                                                   unsigned short* __restrict__ ctx) {
  __shared__ unsigned short Kt[2][64][64];
  __shared__ unsigned short Vt[2][64][64];
  __shared__ unsigned short Pbuf[4][16][64];
  const int bid = ((blockIdx.x & 7) << 7) | (blockIdx.x >> 3);  // bijective, 1024 % 8 == 0
  const int bh = bid >> 4, ib = bid & 15;
  const int b = bh >> 4, h = bh & 15;
  const int tid = threadIdx.x, lane = tid & 63, wv = tid >> 6;
  const int rq = lane >> 4, cq = lane & 15;
  const unsigned short* v1h = v1 + (size_t)bh * 1024 * 64;
  const unsigned short* v2h = v2 + (size_t)bh * 1024 * 64;
  const unsigned short* v4h = v4t + (size_t)bh * 64 * 1024;
  const float* ch = cross + (size_t)bh * 1024;
  const int i0 = ib * 64 + wv * 16;
  // staging constants: lane covers LDS slot (row = base8 + lane/8, chunk = lane%8);
  // source chunk pre-swizzled: c_src = (lane%8) ^ (row%8), row%8 == lane/8 here.
  const int sr = lane >> 3;
  const int sc = ((lane & 7) ^ sr) * 8;  // element offset of 16B chunk
  // Q as B-fragment
  short8 b_q[2];
#pragma unroll
  for (int kk = 0; kk < 2; ++kk)
    b_q[kk] = *(const short8*)(v1h + (size_t)(i0 + cq) * 64 + kk * 32 + rq * 8);
  float m = -3e38f, lsum = 0.f;
  f32x4 o[4] = {};

  // prologue: stage tile 0
#pragma unroll
  for (int p = 0; p < 2; ++p) {
    int r = wv * 8 + p * 32 + sr;
    gload_lds16(v2h + (size_t)r * 64 + sc, &Kt[0][wv * 8 + p * 32][0]);
    gload_lds16(v4h + (size_t)r * 1024 + sc, &Vt[0][wv * 8 + p * 32][0]);
  }
  __syncthreads();

  for (int t = 0; t < 16; ++t) {
    const int cur = t & 1;
    const int jt = t * 64;
    // stage next tile (loads fly during compute; drained by end-of-tile barrier)
    if (t < 15) {
#pragma unroll
      for (int p = 0; p < 2; ++p) {
        int r = wv * 8 + p * 32 + sr;
        gload_lds16(v2h + (size_t)(jt + 64 + r) * 64 + sc, &Kt[cur ^ 1][wv * 8 + p * 32][0]);
        gload_lds16(v4h + (size_t)r * 1024 + jt + 64 + sc, &Vt[cur ^ 1][wv * 8 + p * 32][0]);
      }
    }
    // QK^T swapped: s[mp] rows = keys j, cols = queries q=cq
    f32x4 s[4] = {};
#pragma unroll
    for (int mp = 0; mp < 4; ++mp) {
      const int row = mp * 16 + cq;
      const char* base = (const char*)&Kt[cur][row][0];
#pragma unroll
      for (int kk = 0; kk < 2; ++kk) {
        short8 ak = *(const short8*)(base + ((((kk << 2) | rq) ^ (cq & 7)) << 4));
        s[mp] = __builtin_amdgcn_mfma_f32_16x16x32_bf16(ak, b_q[kk], s[mp], 0, 0, 0);
      }
    }
    // cross bias: j = jt + mp*16 + rq*4 + r
#pragma unroll
    for (int mp = 0; mp < 4; ++mp) {
      float4 cj = *(const float4*)(ch + jt + mp * 16 + rq * 4);
      s[mp][0] += cj.x; s[mp][1] += cj.y; s[mp][2] += cj.z; s[mp][3] += cj.w;
    }
    // online softmax for column q=cq
    float tm = s[0][0];
#pragma unroll
    for (int mp = 0; mp < 4; ++mp)
#pragma unroll
      for (int r = 0; r < 4; ++r) tm = fmaxf(tm, s[mp][r]);
    tm = fmaxf(tm, __shfl_xor(tm, 16));
    tm = fmaxf(tm, __shfl_xor(tm, 32));
    float mn = fmaxf(m, tm);
    float alpha = __expf(m - mn);
    m = mn;
    float ps = 0.f;
#pragma unroll
    for (int mp = 0; mp < 4; ++mp)
#pragma unroll
      for (int r = 0; r < 4; ++r) {
        float p = __expf(s[mp][r] - mn);
        s[mp][r] = p;
        ps += p;
      }
    ps += __shfl_xor(ps, 16);
    ps += __shfl_xor(ps, 32);
    lsum = lsum * alpha + ps;
    // P -> per-wave LDS slice (XOR-swizzled bytes, row = q = cq)
    {
      char* pb = (char*)&Pbuf[wv][cq][0];
      const int sw = (cq & 7) << 4;
#pragma unroll
      for (int mp = 0; mp < 4; ++mp) {
        ushort4 pw;
        pw.x = f2bf(s[mp][0]); pw.y = f2bf(s[mp][1]);
        pw.z = f2bf(s[mp][2]); pw.w = f2bf(s[mp][3]);
        *(ushort4*)(pb + ((mp * 32 + rq * 8) ^ sw)) = pw;
      }
    }
    short8 a_p[2];
    {
      const char* pb = (const char*)&Pbuf[wv][cq][0];
      const int sw = (cq & 7) << 4;
#pragma unroll
      for (int kk = 0; kk < 2; ++kk)
        a_p[kk] = *(const short8*)(pb + ((kk * 64 + rq * 16) ^ sw));
    }
    // rescale O
    float al[4];
#pragma unroll
    for (int r = 0; r < 4; ++r) al[r] = __shfl(alpha, rq * 4 + r);
#pragma unroll
    for (int n = 0; n < 4; ++n)
#pragma unroll
      for (int r = 0; r < 4; ++r) o[n][r] *= al[r];
    // PV: B-fragments from V^T tile (row = d = n*16+cq)
#pragma unroll
    for (int n = 0; n < 4; ++n) {
      const int row = n * 16 + cq;
      const char* base = (const char*)&Vt[cur][row][0];
#pragma unroll
      for (int kk = 0; kk < 2; ++kk) {
        short8 bv = *(const short8*)(base + ((((kk << 2) | rq) ^ (cq & 7)) << 4));
        o[n] = __builtin_amdgcn_mfma_f32_16x16x32_bf16(a_p[kk], bv, o[n], 0, 0, 0);
      }
    }
    __syncthreads();  // all waves done with buf cur; next-tile stages complete
  }
  float li[4];
#pragma unroll
  for (int r = 0; r < 4; ++r) li[r] = __shfl(lsum, rq * 4 + r);
#pragma unroll
  for (int n = 0; n < 4; ++n)
#pragma unroll
    for (int r = 0; r < 4; ++r) {
      float val = o[n][r] / li[r];
      int row = i0 + rq * 4 + r;
      int col = h * 64 + n * 16 + cq;
      ctx[((size_t)b * 1024 + row) * 1024 + col] = f2bf(val);
    }
}

extern "C" void kernel_launch(void* const* d_in, const int* in_sizes, int n_in,
                              void* d_out, int out_size, void* d_ws, size_t ws_size,
                              hipStream_t stream) {
  const int bs = in_sizes[0] / (128 * 1024);  // = 4
  char* w = (char*)d_ws;
  size_t off = 0;
  auto alloc = [&](size_t bytes) -> void* {
    void* p = w + off;
    off += (bytes + 255) & ~(size_t)255;
    return p;
  };
  unsigned short* wfeat_b = (unsigned short*)alloc((size_t)bs * 128 * 1024 * 2);
  unsigned short* vfeat_b = (unsigned short*)alloc((size_t)bs * 1024 * 1024 * 2);
  unsigned short* Ww1b = (unsigned short*)alloc((size_t)1024 * 1024 * 2);
  // Wv1..Wv4 contiguous (each 2MB, 256-aligned) -> one [4096][1024] matrix
  unsigned short* Wv1b = (unsigned short*)alloc((size_t)1024 * 1024 * 2);
  unsigned short* Wv2b = (unsigned short*)alloc((size_t)1024 * 1024 * 2);
  unsigned short* Wv3b = (unsigned short*)alloc((size_t)1024 * 1024 * 2);
  unsigned short* Wv4b = (unsigned short*)alloc((size_t)1024 * 1024 * 2);
  unsigned short* Woutb = (unsigned short*)alloc((size_t)1024 * 1024 * 2);
  unsigned short* w1b = (unsigned short*)alloc((size_t)bs * 16 * 128 * 64 * 2);
  unsigned short* v1b = (unsigned short*)alloc((size_t)bs * 16 * 1024 * 64 * 2);
  unsigned short* v2b = (unsigned short*)alloc((size_t)bs * 16 * 1024 * 64 * 2);
  unsigned short* v3b = (unsigned short*)alloc((size_t)bs * 16 * 1024 * 64 * 2);
  unsigned short* v4tb = (unsigned short*)alloc((size_t)bs * 16 * 64 * 1024 * 2);
  unsigned short* ctxb = (unsigned short*)alloc((size_t)bs * 1024 * 1024 * 2);
  float* crossb = (float*)alloc((size_t)bs * 16 * 1024 * 4);
  float* biascat = (float*)alloc((size_t)4096 * 4);

  auto cvt = [&](const void* src, unsigned short* dst, int n) {
    cvt_f2b<<<(n / 4 + 255) / 256, 256, 0, stream>>>((const float*)src, dst, n);
  };
  cvt(d_in[0], wfeat_b, bs * 128 * 1024);
  cvt(d_in[1], vfeat_b, bs * 1024 * 1024);
  cvt(d_in[2], Ww1b, 1024 * 1024);
  cvt(d_in[4], Wv1b, 1024 * 1024);
  cvt(d_in[6], Wv2b, 1024 * 1024);
  cvt(d_in[8], Wv3b, 1024 * 1024);
  cvt(d_in[10], Wv4b, 1024 * 1024);
  cvt(d_in[12], Woutb, 1024 * 1024);
  gather_bias<<<16, 256, 0, stream>>>((const float*)d_in[5], (const float*)d_in[7],
                                      (const float*)d_in[9], (const float*)d_in[11], biascat);
  zero_f32<<<64, 256, 0, stream>>>(crossb, bs * 16 * 1024 / 4);

  dim3 blk(256);
  // w1 projection (M = bs*128)
  gemm_bt<0><<<dim3(bs * 128 / 128, 8), blk, 0, stream>>>(wfeat_b, Ww1b, (const float*)d_in[3],
                                                          w1b, nullptr, nullptr, nullptr, 7);
  // fused v1..v4 projection: M = bs*1024, N = 4096 -> 1024 blocks (4/CU)
  gemm_bt<3><<<dim3(bs * 1024 / 128, 32), blk, 0, stream>>>(vfeat_b, Wv1b, biascat,
                                                            v1b, v2b, v3b, v4tb, 10);
  // cross bias
  cross_kernel<<<bs * 16 * 2, blk, 0, stream>>>(w1b, v3b, crossb);
  // fused attention
  attn_kernel<<<bs * 16 * 16, blk, 0, stream>>>(v1b, v2b, v4tb, crossb, ctxb);
  // output projection
  gemm_bt<2><<<dim3(bs * 1024 / 128, 8), blk, 0, stream>>>(ctxb, Woutb, (const float*)d_in[13],
                                                           (float*)d_out, nullptr, nullptr, nullptr, 0);
}

// Round 10
// 320.311 us; speedup vs baseline: 1.4633x; 1.0048x over previous
//
#include <hip/hip_runtime.h>

typedef __attribute__((ext_vector_type(8))) short short8;
typedef __attribute__((ext_vector_type(4))) float f32x4;

__device__ __forceinline__ unsigned short f2bf(float f) {
  unsigned int x = __float_as_uint(f);
  x += 0x7fffu + ((x >> 16) & 1u);
  return (unsigned short)(x >> 16);
}

__device__ __forceinline__ void gload_lds16(const void* g, void* l) {
  __builtin_amdgcn_global_load_lds((const __attribute__((address_space(1))) unsigned int*)g,
                                   (__attribute__((address_space(3))) unsigned int*)l, 16, 0, 0);
}

// ---------------- f32 -> bf16 conversion ----------------
__global__ void cvt_f2b(const float* __restrict__ s, unsigned short* __restrict__ d, int n) {
  int i = (blockIdx.x * 256 + threadIdx.x) * 4;
  if (i < n) {
    float4 v = *(const float4*)(s + i);
    ushort4 o;
    o.x = f2bf(v.x); o.y = f2bf(v.y); o.z = f2bf(v.z); o.w = f2bf(v.w);
    *(ushort4*)(d + i) = o;
  }
}

__global__ void gather_bias(const float* __restrict__ b0, const float* __restrict__ b1,
                            const float* __restrict__ b2, const float* __restrict__ b3,
                            float* __restrict__ out) {
  int i = blockIdx.x * 256 + threadIdx.x;  // 4096 total
  const float* src = (i < 1024) ? b0 : (i < 2048) ? b1 : (i < 3072) ? b2 : b3;
  out[i] = src[i & 1023];
}

__global__ void zero_f32(float* __restrict__ p, int n4) {
  int i = blockIdx.x * 256 + threadIdx.x;
  if (i < n4) *(float4*)(p + i * 4) = float4{0.f, 0.f, 0.f, 0.f};
}

// ======== Pipelined GEMM: Y[M x N] = X[M x 1024] @ W^T + bias ========
// Double-buffered K-tiles (BK=64), raw s_barrier + counted vmcnt(8) (next tile's
// 8 loads/thread stay in flight across barriers), XOR-swizzled LDS (pre-swizzled
// global source, swizzled ds_read), 4 quadrant sub-phases/K-tile with setprio.
// MODE 0: bf16 head layout [b][16][Nn][64]; MODE 2: f32 [M][1024];
// MODE 3: fused v-proj N=4096: slabs 0-2 head layout to o0..o2, slab 3 transposed to o3.
template<int MODE, int BM, int BN, int WM, int WN>
__global__ __launch_bounds__(WM * WN * 64, 2) void gemm_pipe(
    const unsigned short* __restrict__ X, const unsigned short* __restrict__ Wt,
    const float* __restrict__ bias, void* __restrict__ o0, void* __restrict__ o1,
    void* __restrict__ o2, void* __restrict__ o3, int nnShift) {
  constexpr int T = WM * WN * 64;
  constexpr int WAVES = WM * WN;
  constexpr int MR = BM / WM / 16;   // M frags per wave
  constexpr int NR = BN / WN / 16;   // N frags per wave
  constexpr int MH = MR / 2, NH = NR / 2;
  constexpr int AI = BM * 8 / T;     // gload insts/thread for A tile (=4)
  constexpr int BI = BN * 8 / T;     // (=4)
  constexpr int NT = 1024 / 64;      // 16 K-tiles

  __shared__ unsigned short As[2][BM][64];
  __shared__ unsigned short Bs[2][BN][64];

  const int tid = threadIdx.x, lane = tid & 63, wv = tid >> 6;
  const int wm = wv % WM, wn = wv / WM;
  const int wMb = wm * (BM / WM), wNb = wn * (BN / WN);
  const int rowbase = blockIdx.x * BM, colbase = blockIdx.y * BN;
  const int rq = lane >> 4, cq = lane & 15;

  f32x4 acc[MR][NR] = {};

  // stage K-tile kt into dbuf slot s: linear LDS dest, source chunk pre-swizzled
  auto stage = [&](int s, int kt) {
#pragma unroll
    for (int j = 0; j < AI; ++j) {
      int cb = (j * WAVES + wv) * 64;          // wave-uniform chunk base
      int row = (cb + lane) >> 3;
      int srcc = (lane & 7) ^ (row & 7);
      gload_lds16(X + (size_t)(rowbase + row) * 1024 + kt * 64 + srcc * 8,
                  &As[s][cb >> 3][0]);
    }
#pragma unroll
    for (int j = 0; j < BI; ++j) {
      int cb = (j * WAVES + wv) * 64;
      int row = (cb + lane) >> 3;
      int srcc = (lane & 7) ^ (row & 7);
      gload_lds16(Wt + (size_t)(colbase + row) * 1024 + kt * 64 + srcc * 8,
                  &Bs[s][cb >> 3][0]);
    }
  };

  auto ktile = [&](int t, bool last) {
    if (last) asm volatile("s_waitcnt vmcnt(0)" ::: "memory");
    else      asm volatile("s_waitcnt vmcnt(8)" ::: "memory");
    __builtin_amdgcn_s_barrier();
    asm volatile("" ::: "memory");
    const int s = t & 1;
#pragma unroll
    for (int qd = 0; qd < 4; ++qd) {
      const int mh = qd >> 1, nh = qd & 1;
      short8 af[MH][2], bf[NH][2];
#pragma unroll
      for (int i = 0; i < MH; ++i)
#pragma unroll
        for (int kk = 0; kk < 2; ++kk) {
          int row = wMb + (mh * MH + i) * 16 + cq;
          int pc = (kk * 4 + rq) ^ (cq & 7);
          af[i][kk] = *(const short8*)(&As[s][row][pc * 8]);
        }
#pragma unroll
      for (int jf = 0; jf < NH; ++jf)
#pragma unroll
        for (int kk = 0; kk < 2; ++kk) {
          int row = wNb + (nh * NH + jf) * 16 + cq;
          int pc = (kk * 4 + rq) ^ (cq & 7);
          bf[jf][kk] = *(const short8*)(&Bs[s][row][pc * 8]);
        }
      __builtin_amdgcn_s_setprio(1);
#pragma unroll
      for (int i = 0; i < MH; ++i)
#pragma unroll
        for (int jf = 0; jf < NH; ++jf)
#pragma unroll
          for (int kk = 0; kk < 2; ++kk)
            acc[mh * MH + i][nh * NH + jf] = __builtin_amdgcn_mfma_f32_16x16x32_bf16(
                af[i][kk], bf[jf][kk], acc[mh * MH + i][nh * NH + jf], 0, 0, 0);
      __builtin_amdgcn_s_setprio(0);
      asm volatile("" ::: "memory");
      __builtin_amdgcn_s_barrier();
      asm volatile("" ::: "memory");
    }
    if (t + 2 < NT) stage(s, t + 2);  // S[s] free after last quadrant barrier
  };

  // prologue: stage tiles 0 and 1 (16 loads/thread outstanding)
  stage(0, 0);
  stage(1, 1);
  for (int t = 0; t < NT - 1; ++t) ktile(t, false);
  ktile(NT - 1, true);

  // epilogue
#pragma unroll
  for (int m = 0; m < MR; ++m)
#pragma unroll
    for (int n = 0; n < NR; ++n)
#pragma unroll
      for (int r = 0; r < 4; ++r) {
        int grow = rowbase + wMb + m * 16 + rq * 4 + r;
        int gcol = colbase + wNb + n * 16 + cq;
        float val = acc[m][n][r] + bias[gcol];
        if (MODE == 2) {
          ((float*)o0)[(size_t)grow * 1024 + gcol] = val;
        } else if (MODE == 0) {
          int bb = grow >> nnShift;
          int nr = grow & ((1 << nnShift) - 1);
          int hh = gcol >> 6, dd = gcol & 63;
          ((unsigned short*)o0)[((((size_t)bb * 16 + hh) << nnShift) + nr) * 64 + dd] = f2bf(val);
        } else {  // MODE 3
          int which = gcol >> 10;  // uniform per block (BN=256 never crosses a 1024 slab)
          int lcol = gcol & 1023;
          int bb = grow >> 10, nr = grow & 1023;
          int hh = lcol >> 6, dd = lcol & 63;
          void* op = (which == 0) ? o0 : (which == 1) ? o1 : (which == 2) ? o2 : o3;
          if (which < 3)
            ((unsigned short*)op)[((((size_t)bb * 16 + hh) << 10) + nr) * 64 + dd] = f2bf(val);
          else
            ((unsigned short*)op)[(((size_t)bb * 16 + hh) * 64 + dd) * 1024 + nr] = f2bf(val);
        }
      }
}

// ---------------- cross path: cross[b,h,j] += sum_{w in half} softmax_j(w1[w] . v3[j]) ----------------
__global__ __launch_bounds__(256) void cross_kernel(const unsigned short* __restrict__ w1,
                                                    const unsigned short* __restrict__ v3,
                                                    float* __restrict__ cross) {
  __shared__ float cbuf[4][1024];
  const int tid = threadIdx.x, lane = tid & 63, wv = tid >> 6;
  const int rq = lane >> 4, cq = lane & 15;
  for (int i = tid; i < 4096; i += 256) ((float*)cbuf)[i] = 0.f;
  __syncthreads();
  const int bh = blockIdx.x >> 1, half = blockIdx.x & 1;
  const unsigned short* w1h = w1 + (size_t)bh * 128 * 64;
  const unsigned short* v3h = v3 + (size_t)bh * 1024 * 64;
  const int w0 = half * 64 + wv * 16;
  short8 a_w[2];
#pragma unroll
  for (int kk = 0; kk < 2; ++kk)
    a_w[kk] = *(const short8*)(w1h + (size_t)(w0 + cq) * 64 + kk * 32 + rq * 8);
  float mrow[4], lrow[4];
#pragma unroll
  for (int r = 0; r < 4; ++r) { mrow[r] = -3e38f; lrow[r] = 0.f; }
  for (int jt = 0; jt < 1024; jt += 64) {
    f32x4 s[4] = {};
#pragma unroll
    for (int n = 0; n < 4; ++n) {
      short8 bk[2];
#pragma unroll
      for (int kk = 0; kk < 2; ++kk)
        bk[kk] = *(const short8*)(v3h + (size_t)(jt + n * 16 + cq) * 64 + kk * 32 + rq * 8);
#pragma unroll
      for (int kk = 0; kk < 2; ++kk)
        s[n] = __builtin_amdgcn_mfma_f32_16x16x32_bf16(a_w[kk], bk[kk], s[n], 0, 0, 0);
    }
    float tm[4], ps[4];
#pragma unroll
    for (int r = 0; r < 4; ++r)
      tm[r] = fmaxf(fmaxf(s[0][r], s[1][r]), fmaxf(s[2][r], s[3][r]));
    for (int off = 1; off < 16; off <<= 1)
#pragma unroll
      for (int r = 0; r < 4; ++r) tm[r] = fmaxf(tm[r], __shfl_xor(tm[r], off));
#pragma unroll
    for (int r = 0; r < 4; ++r) {
      float mn = fmaxf(mrow[r], tm[r]);
      float al = __expf(mrow[r] - mn);
      mrow[r] = mn;
      float p = 0.f;
#pragma unroll
      for (int n = 0; n < 4; ++n) p += __expf(s[n][r] - mn);
      ps[r] = p;
      lrow[r] *= al;
    }
    for (int off = 1; off < 16; off <<= 1)
#pragma unroll
      for (int r = 0; r < 4; ++r) ps[r] += __shfl_xor(ps[r], off);
#pragma unroll
    for (int r = 0; r < 4; ++r) lrow[r] += ps[r];
  }
  float rl[4];
#pragma unroll
  for (int r = 0; r < 4; ++r) rl[r] = 1.f / lrow[r];
  for (int jt = 0; jt < 1024; jt += 64) {
    f32x4 s[4] = {};
#pragma unroll
    for (int n = 0; n < 4; ++n) {
      short8 bk[2];
#pragma unroll
      for (int kk = 0; kk < 2; ++kk)
        bk[kk] = *(const short8*)(v3h + (size_t)(jt + n * 16 + cq) * 64 + kk * 32 + rq * 8);
#pragma unroll
      for (int kk = 0; kk < 2; ++kk)
        s[n] = __builtin_amdgcn_mfma_f32_16x16x32_bf16(a_w[kk], bk[kk], s[n], 0, 0, 0);
    }
    float colsum[4] = {0.f, 0.f, 0.f, 0.f};
#pragma unroll
    for (int n = 0; n < 4; ++n)
#pragma unroll
      for (int r = 0; r < 4; ++r)
        colsum[n] += __expf(s[n][r] - mrow[r]) * rl[r];
#pragma unroll
    for (int n = 0; n < 4; ++n) {
      colsum[n] += __shfl_xor(colsum[n], 16);
      colsum[n] += __shfl_xor(colsum[n], 32);
    }
    if (lane < 16) {
#pragma unroll
      for (int n = 0; n < 4; ++n) cbuf[wv][jt + n * 16 + lane] += colsum[n];
    }
  }
  __syncthreads();
  for (int j = tid; j < 1024; j += 256)
    atomicAdd(&cross[(size_t)bh * 1024 + j], cbuf[0][j] + cbuf[1][j] + cbuf[2][j] + cbuf[3][j]);
}

// ---------------- fused self-attention, LDS-staged K/V, double-buffered ----------------
__global__ __launch_bounds__(256) void attn_kernel(const unsigned short* __restrict__ v1,
                                                   const unsigned short* __restrict__ v2,
                                                   const unsigned short* __restrict__ v4t,
                                                   const float* __restrict__ cross,
                                                   unsigned short* __restrict__ ctx) {
  __shared__ unsigned short Kt[2][64][64];
  __shared__ unsigned short Vt[2][64][64];
  __shared__ unsigned short Pbuf[4][16][64];
  const int bid = ((blockIdx.x & 7) << 7) | (blockIdx.x >> 3);  // bijective, 1024 % 8 == 0
  const int bh = bid >> 4, ib = bid & 15;
  const int b = bh >> 4, h = bh & 15;
  const int tid = threadIdx.x, lane = tid & 63, wv = tid >> 6;
  const int rq = lane >> 4, cq = lane & 15;
  const unsigned short* v1h = v1 + (size_t)bh * 1024 * 64;
  const unsigned short* v2h = v2 + (size_t)bh * 1024 * 64;
  const unsigned short* v4h = v4t + (size_t)bh * 64 * 1024;
  const float* ch = cross + (size_t)bh * 1024;
  const int i0 = ib * 64 + wv * 16;
  const int sr = lane >> 3;
  const int sc = ((lane & 7) ^ sr) * 8;
  short8 b_q[2];
#pragma unroll
  for (int kk = 0; kk < 2; ++kk)
    b_q[kk] = *(const short8*)(v1h + (size_t)(i0 + cq) * 64 + kk * 32 + rq * 8);
  float m = -3e38f, lsum = 0.f;
  f32x4 o[4] = {};

#pragma unroll
  for (int p = 0; p < 2; ++p) {
    int r = wv * 8 + p * 32 + sr;
    gload_lds16(v2h + (size_t)r * 64 + sc, &Kt[0][wv * 8 + p * 32][0]);
    gload_lds16(v4h + (size_t)r * 1024 + sc, &Vt[0][wv * 8 + p * 32][0]);
  }
  __syncthreads();

  for (int t = 0; t < 16; ++t) {
    const int cur = t & 1;
    const int jt = t * 64;
    if (t < 15) {
#pragma unroll
      for (int p = 0; p < 2; ++p) {
        int r = wv * 8 + p * 32 + sr;
        gload_lds16(v2h + (size_t)(jt + 64 + r) * 64 + sc, &Kt[cur ^ 1][wv * 8 + p * 32][0]);
        gload_lds16(v4h + (size_t)r * 1024 + jt + 64 + sc, &Vt[cur ^ 1][wv * 8 + p * 32][0]);
      }
    }
    f32x4 s[4] = {};
#pragma unroll
    for (int mp = 0; mp < 4; ++mp) {
      const int row = mp * 16 + cq;
      const char* base = (const char*)&Kt[cur][row][0];
#pragma unroll
      for (int kk = 0; kk < 2; ++kk) {
        short8 ak = *(const short8*)(base + ((((kk << 2) | rq) ^ (cq & 7)) << 4));
        s[mp] = __builtin_amdgcn_mfma_f32_16x16x32_bf16(ak, b_q[kk], s[mp], 0, 0, 0);
      }
    }
#pragma unroll
    for (int mp = 0; mp < 4; ++mp) {
      float4 cj = *(const float4*)(ch + jt + mp * 16 + rq * 4);
      s[mp][0] += cj.x; s[mp][1] += cj.y; s[mp][2] += cj.z; s[mp][3] += cj.w;
    }
    float tm = s[0][0];
#pragma unroll
    for (int mp = 0; mp < 4; ++mp)
#pragma unroll
      for (int r = 0; r < 4; ++r) tm = fmaxf(tm, s[mp][r]);
    tm = fmaxf(tm, __shfl_xor(tm, 16));
    tm = fmaxf(tm, __shfl_xor(tm, 32));
    float mn = fmaxf(m, tm);
    float alpha = __expf(m - mn);
    m = mn;
    float ps = 0.f;
#pragma unroll
    for (int mp = 0; mp < 4; ++mp)
#pragma unroll
      for (int r = 0; r < 4; ++r) {
        float p = __expf(s[mp][r] - mn);
        s[mp][r] = p;
        ps += p;
      }
    ps += __shfl_xor(ps, 16);
    ps += __shfl_xor(ps, 32);
    lsum = lsum * alpha + ps;
    {
      char* pb = (char*)&Pbuf[wv][cq][0];
      const int sw = (cq & 7) << 4;
#pragma unroll
      for (int mp = 0; mp < 4; ++mp) {
        ushort4 pw;
        pw.x = f2bf(s[mp][0]); pw.y = f2bf(s[mp][1]);
        pw.z = f2bf(s[mp][2]); pw.w = f2bf(s[mp][3]);
        *(ushort4*)(pb + ((mp * 32 + rq * 8) ^ sw)) = pw;
      }
    }
    short8 a_p[2];
    {
      const char* pb = (const char*)&Pbuf[wv][cq][0];
      const int sw = (cq & 7) << 4;
#pragma unroll
      for (int kk = 0; kk < 2; ++kk)
        a_p[kk] = *(const short8*)(pb + ((kk * 64 + rq * 16) ^ sw));
    }
    float al[4];
#pragma unroll
    for (int r = 0; r < 4; ++r) al[r] = __shfl(alpha, rq * 4 + r);
#pragma unroll
    for (int n = 0; n < 4; ++n)
#pragma unroll
      for (int r = 0; r < 4; ++r) o[n][r] *= al[r];
#pragma unroll
    for (int n = 0; n < 4; ++n) {
      const int row = n * 16 + cq;
      const char* base = (const char*)&Vt[cur][row][0];
#pragma unroll
      for (int kk = 0; kk < 2; ++kk) {
        short8 bv = *(const short8*)(base + ((((kk << 2) | rq) ^ (cq & 7)) << 4));
        o[n] = __builtin_amdgcn_mfma_f32_16x16x32_bf16(a_p[kk], bv, o[n], 0, 0, 0);
      }
    }
    __syncthreads();
  }
  float li[4];
#pragma unroll
  for (int r = 0; r < 4; ++r) li[r] = __shfl(lsum, rq * 4 + r);
#pragma unroll
  for (int n = 0; n < 4; ++n)
#pragma unroll
    for (int r = 0; r < 4; ++r) {
      float val = o[n][r] / li[r];
      int row = i0 + rq * 4 + r;
      int col = h * 64 + n * 16 + cq;
      ctx[((size_t)b * 1024 + row) * 1024 + col] = f2bf(val);
    }
}

extern "C" void kernel_launch(void* const* d_in, const int* in_sizes, int n_in,
                              void* d_out, int out_size, void* d_ws, size_t ws_size,
                              hipStream_t stream) {
  const int bs = in_sizes[0] / (128 * 1024);  // = 4
  char* w = (char*)d_ws;
  size_t off = 0;
  auto alloc = [&](size_t bytes) -> void* {
    void* p = w + off;
    off += (bytes + 255) & ~(size_t)255;
    return p;
  };
  unsigned short* wfeat_b = (unsigned short*)alloc((size_t)bs * 128 * 1024 * 2);
  unsigned short* vfeat_b = (unsigned short*)alloc((size_t)bs * 1024 * 1024 * 2);
  unsigned short* Ww1b = (unsigned short*)alloc((size_t)1024 * 1024 * 2);
  // Wv1..Wv4 contiguous (each 2MB, 256-aligned) -> one [4096][1024] matrix
  unsigned short* Wv1b = (unsigned short*)alloc((size_t)1024 * 1024 * 2);
  unsigned short* Wv2b = (unsigned short*)alloc((size_t)1024 * 1024 * 2);
  unsigned short* Wv3b = (unsigned short*)alloc((size_t)1024 * 1024 * 2);
  unsigned short* Wv4b = (unsigned short*)alloc((size_t)1024 * 1024 * 2);
  unsigned short* Woutb = (unsigned short*)alloc((size_t)1024 * 1024 * 2);
  unsigned short* w1b = (unsigned short*)alloc((size_t)bs * 16 * 128 * 64 * 2);
  unsigned short* v1b = (unsigned short*)alloc((size_t)bs * 16 * 1024 * 64 * 2);
  unsigned short* v2b = (unsigned short*)alloc((size_t)bs * 16 * 1024 * 64 * 2);
  unsigned short* v3b = (unsigned short*)alloc((size_t)bs * 16 * 1024 * 64 * 2);
  unsigned short* v4tb = (unsigned short*)alloc((size_t)bs * 16 * 64 * 1024 * 2);
  unsigned short* ctxb = (unsigned short*)alloc((size_t)bs * 1024 * 1024 * 2);
  float* crossb = (float*)alloc((size_t)bs * 16 * 1024 * 4);
  float* biascat = (float*)alloc((size_t)4096 * 4);

  auto cvt = [&](const void* src, unsigned short* dst, int n) {
    cvt_f2b<<<(n / 4 + 255) / 256, 256, 0, stream>>>((const float*)src, dst, n);
  };
  cvt(d_in[0], wfeat_b, bs * 128 * 1024);
  cvt(d_in[1], vfeat_b, bs * 1024 * 1024);
  cvt(d_in[2], Ww1b, 1024 * 1024);
  cvt(d_in[4], Wv1b, 1024 * 1024);
  cvt(d_in[6], Wv2b, 1024 * 1024);
  cvt(d_in[8], Wv3b, 1024 * 1024);
  cvt(d_in[10], Wv4b, 1024 * 1024);
  cvt(d_in[12], Woutb, 1024 * 1024);
  gather_bias<<<16, 256, 0, stream>>>((const float*)d_in[5], (const float*)d_in[7],
                                      (const float*)d_in[9], (const float*)d_in[11], biascat);
  zero_f32<<<64, 256, 0, stream>>>(crossb, bs * 16 * 1024 / 4);

  // w1 projection: M=512, 128^2 tiles -> grid (4,8)
  gemm_pipe<0, 128, 128, 2, 2><<<dim3(4, 8), 256, 0, stream>>>(
      wfeat_b, Ww1b, (const float*)d_in[3], w1b, nullptr, nullptr, nullptr, 7);
  // fused v1..v4 projection: M=4096, N=4096, 256^2 tiles -> grid (16,16), 512 thr
  gemm_pipe<3, 256, 256, 2, 4><<<dim3(16, 16), 512, 0, stream>>>(
      vfeat_b, Wv1b, biascat, v1b, v2b, v3b, v4tb, 10);
  // cross bias
  cross_kernel<<<bs * 16 * 2, 256, 0, stream>>>(w1b, v3b, crossb);
  // fused attention
  attn_kernel<<<bs * 16 * 16, 256, 0, stream>>>(v1b, v2b, v4tb, crossb, ctxb);
  // output projection: M=4096, N=1024, 128^2 tiles -> grid (32,8)
  gemm_pipe<2, 128, 128, 2, 2><<<dim3(32, 8), 256, 0, stream>>>(
      ctxb, Woutb, (const float*)d_in[13], (float*)d_out, nullptr, nullptr, nullptr, 0);
}

// Round 11
// 308.315 us; speedup vs baseline: 1.5203x; 1.0389x over previous
//
#include <hip/hip_runtime.h>

typedef __attribute__((ext_vector_type(8))) short short8;
typedef __attribute__((ext_vector_type(4))) float f32x4;

__device__ __forceinline__ unsigned short f2bf(float f) {
  unsigned int x = __float_as_uint(f);
  x += 0x7fffu + ((x >> 16) & 1u);
  return (unsigned short)(x >> 16);
}

__device__ __forceinline__ void gload_lds16(const void* g, void* l) {
  __builtin_amdgcn_global_load_lds((const __attribute__((address_space(1))) unsigned int*)g,
                                   (__attribute__((address_space(3))) unsigned int*)l, 16, 0, 0);
}

// ---------------- f32 -> bf16 conversion ----------------
__global__ void cvt_f2b(const float* __restrict__ s, unsigned short* __restrict__ d, int n) {
  int i = (blockIdx.x * 256 + threadIdx.x) * 4;
  if (i < n) {
    float4 v = *(const float4*)(s + i);
    ushort4 o;
    o.x = f2bf(v.x); o.y = f2bf(v.y); o.z = f2bf(v.z); o.w = f2bf(v.w);
    *(ushort4*)(d + i) = o;
  }
}

__global__ void gather_bias(const float* __restrict__ b0, const float* __restrict__ b1,
                            const float* __restrict__ b2, const float* __restrict__ b3,
                            float* __restrict__ out) {
  int i = blockIdx.x * 256 + threadIdx.x;  // 4096 total
  const float* src = (i < 1024) ? b0 : (i < 2048) ? b1 : (i < 3072) ? b2 : b3;
  out[i] = src[i & 1023];
}

__global__ void zero_f32(float* __restrict__ p, int n4) {
  int i = blockIdx.x * 256 + threadIdx.x;
  if (i < n4) *(float4*)(p + i * 4) = float4{0.f, 0.f, 0.f, 0.f};
}

// ======== Pipelined GEMM: Y[M x N] = X[M x 1024] @ W^T + bias ========
// Double-buffered K-tiles (BK=64), raw s_barrier + counted vmcnt(8), XOR-swizzled LDS.
// R10 restructure: MINIMAL LDS reads — all B-frags hoisted once per K-tile, A-frags
// once per M-half (24 ds_read_b128/wave/tile at 256^2, was 48; 16 at 128^2, was 32).
// Round-10 counters showed LDS-read throughput (not conflicts, now 0) is the floor.
// 2 barriers/tile instead of 8.
// MODE 0: bf16 head layout [b][16][Nn][64]; MODE 2: f32 [M][1024];
// MODE 3: fused v-proj N=4096: slabs 0-2 head layout to o0..o2, slab 3 transposed to o3.
template<int MODE, int BM, int BN, int WM, int WN>
__global__ __launch_bounds__(WM * WN * 64, 2) void gemm_pipe(
    const unsigned short* __restrict__ X, const unsigned short* __restrict__ Wt,
    const float* __restrict__ bias, void* __restrict__ o0, void* __restrict__ o1,
    void* __restrict__ o2, void* __restrict__ o3, int nnShift) {
  constexpr int T = WM * WN * 64;
  constexpr int WAVES = WM * WN;
  constexpr int MR = BM / WM / 16;   // M frags per wave
  constexpr int NR = BN / WN / 16;   // N frags per wave
  constexpr int MH = MR / 2;
  constexpr int AI = BM * 8 / T;     // gload insts/thread for A tile (=4)
  constexpr int BI = BN * 8 / T;     // (=4)
  constexpr int NT = 1024 / 64;      // 16 K-tiles

  __shared__ unsigned short As[2][BM][64];
  __shared__ unsigned short Bs[2][BN][64];

  const int tid = threadIdx.x, lane = tid & 63, wv = tid >> 6;
  const int wm = wv % WM, wn = wv / WM;
  const int wMb = wm * (BM / WM), wNb = wn * (BN / WN);
  const int rowbase = blockIdx.x * BM, colbase = blockIdx.y * BN;
  const int rq = lane >> 4, cq = lane & 15;

  f32x4 acc[MR][NR] = {};

  // stage K-tile kt into dbuf slot s: linear LDS dest, source chunk pre-swizzled
  auto stage = [&](int s, int kt) {
#pragma unroll
    for (int j = 0; j < AI; ++j) {
      int cb = (j * WAVES + wv) * 64;          // wave-uniform chunk base
      int row = (cb + lane) >> 3;
      int srcc = (lane & 7) ^ (row & 7);
      gload_lds16(X + (size_t)(rowbase + row) * 1024 + kt * 64 + srcc * 8,
                  &As[s][cb >> 3][0]);
    }
#pragma unroll
    for (int j = 0; j < BI; ++j) {
      int cb = (j * WAVES + wv) * 64;
      int row = (cb + lane) >> 3;
      int srcc = (lane & 7) ^ (row & 7);
      gload_lds16(Wt + (size_t)(colbase + row) * 1024 + kt * 64 + srcc * 8,
                  &Bs[s][cb >> 3][0]);
    }
  };

  auto ktile = [&](int t, bool last) {
    if (last) asm volatile("s_waitcnt vmcnt(0)" ::: "memory");
    else      asm volatile("s_waitcnt vmcnt(8)" ::: "memory");
    __builtin_amdgcn_s_barrier();
    asm volatile("" ::: "memory");
    const int s = t & 1;
    // hoist ALL B-fragments once per K-tile (NR*2 reads)
    short8 bf[NR][2];
#pragma unroll
    for (int jf = 0; jf < NR; ++jf)
#pragma unroll
      for (int kk = 0; kk < 2; ++kk) {
        int row = wNb + jf * 16 + cq;
        int pc = (kk * 4 + rq) ^ (cq & 7);
        bf[jf][kk] = *(const short8*)(&Bs[s][row][pc * 8]);
      }
    // two M-halves: A-fragments read once each (MH*2 reads per half)
#pragma unroll
    for (int mh = 0; mh < 2; ++mh) {
      short8 af[MH][2];
#pragma unroll
      for (int i = 0; i < MH; ++i)
#pragma unroll
        for (int kk = 0; kk < 2; ++kk) {
          int row = wMb + (mh * MH + i) * 16 + cq;
          int pc = (kk * 4 + rq) ^ (cq & 7);
          af[i][kk] = *(const short8*)(&As[s][row][pc * 8]);
        }
      __builtin_amdgcn_s_setprio(1);
#pragma unroll
      for (int i = 0; i < MH; ++i)
#pragma unroll
        for (int jf = 0; jf < NR; ++jf)
#pragma unroll
          for (int kk = 0; kk < 2; ++kk)
            acc[mh * MH + i][jf] = __builtin_amdgcn_mfma_f32_16x16x32_bf16(
                af[i][kk], bf[jf][kk], acc[mh * MH + i][jf], 0, 0, 0);
      __builtin_amdgcn_s_setprio(0);
    }
    asm volatile("" ::: "memory");
    __builtin_amdgcn_s_barrier();
    asm volatile("" ::: "memory");
    if (t + 2 < NT) stage(s, t + 2);  // S[s] free after end-of-tile barrier
  };

  // prologue: stage tiles 0 and 1 (16 loads/thread outstanding)
  stage(0, 0);
  stage(1, 1);
  for (int t = 0; t < NT - 1; ++t) ktile(t, false);
  ktile(NT - 1, true);

  // epilogue
#pragma unroll
  for (int m = 0; m < MR; ++m)
#pragma unroll
    for (int n = 0; n < NR; ++n)
#pragma unroll
      for (int r = 0; r < 4; ++r) {
        int grow = rowbase + wMb + m * 16 + rq * 4 + r;
        int gcol = colbase + wNb + n * 16 + cq;
        float val = acc[m][n][r] + bias[gcol];
        if (MODE == 2) {
          ((float*)o0)[(size_t)grow * 1024 + gcol] = val;
        } else if (MODE == 0) {
          int bb = grow >> nnShift;
          int nr = grow & ((1 << nnShift) - 1);
          int hh = gcol >> 6, dd = gcol & 63;
          ((unsigned short*)o0)[((((size_t)bb * 16 + hh) << nnShift) + nr) * 64 + dd] = f2bf(val);
        } else {  // MODE 3
          int which = gcol >> 10;  // uniform per block (BN=256 never crosses a 1024 slab)
          int lcol = gcol & 1023;
          int bb = grow >> 10, nr = grow & 1023;
          int hh = lcol >> 6, dd = lcol & 63;
          void* op = (which == 0) ? o0 : (which == 1) ? o1 : (which == 2) ? o2 : o3;
          if (which < 3)
            ((unsigned short*)op)[((((size_t)bb * 16 + hh) << 10) + nr) * 64 + dd] = f2bf(val);
          else
            ((unsigned short*)op)[(((size_t)bb * 16 + hh) * 64 + dd) * 1024 + nr] = f2bf(val);
        }
      }
}

// ---------------- cross path: cross[b,h,j] += sum_{w in half} softmax_j(w1[w] . v3[j]) ----------------
__global__ __launch_bounds__(256) void cross_kernel(const unsigned short* __restrict__ w1,
                                                    const unsigned short* __restrict__ v3,
                                                    float* __restrict__ cross) {
  __shared__ float cbuf[4][1024];
  const int tid = threadIdx.x, lane = tid & 63, wv = tid >> 6;
  const int rq = lane >> 4, cq = lane & 15;
  for (int i = tid; i < 4096; i += 256) ((float*)cbuf)[i] = 0.f;
  __syncthreads();
  const int bh = blockIdx.x >> 1, half = blockIdx.x & 1;
  const unsigned short* w1h = w1 + (size_t)bh * 128 * 64;
  const unsigned short* v3h = v3 + (size_t)bh * 1024 * 64;
  const int w0 = half * 64 + wv * 16;
  short8 a_w[2];
#pragma unroll
  for (int kk = 0; kk < 2; ++kk)
    a_w[kk] = *(const short8*)(w1h + (size_t)(w0 + cq) * 64 + kk * 32 + rq * 8);
  float mrow[4], lrow[4];
#pragma unroll
  for (int r = 0; r < 4; ++r) { mrow[r] = -3e38f; lrow[r] = 0.f; }
  for (int jt = 0; jt < 1024; jt += 64) {
    f32x4 s[4] = {};
#pragma unroll
    for (int n = 0; n < 4; ++n) {
      short8 bk[2];
#pragma unroll
      for (int kk = 0; kk < 2; ++kk)
        bk[kk] = *(const short8*)(v3h + (size_t)(jt + n * 16 + cq) * 64 + kk * 32 + rq * 8);
#pragma unroll
      for (int kk = 0; kk < 2; ++kk)
        s[n] = __builtin_amdgcn_mfma_f32_16x16x32_bf16(a_w[kk], bk[kk], s[n], 0, 0, 0);
    }
    float tm[4], ps[4];
#pragma unroll
    for (int r = 0; r < 4; ++r)
      tm[r] = fmaxf(fmaxf(s[0][r], s[1][r]), fmaxf(s[2][r], s[3][r]));
    for (int off = 1; off < 16; off <<= 1)
#pragma unroll
      for (int r = 0; r < 4; ++r) tm[r] = fmaxf(tm[r], __shfl_xor(tm[r], off));
#pragma unroll
    for (int r = 0; r < 4; ++r) {
      float mn = fmaxf(mrow[r], tm[r]);
      float al = __expf(mrow[r] - mn);
      mrow[r] = mn;
      float p = 0.f;
#pragma unroll
      for (int n = 0; n < 4; ++n) p += __expf(s[n][r] - mn);
      ps[r] = p;
      lrow[r] *= al;
    }
    for (int off = 1; off < 16; off <<= 1)
#pragma unroll
      for (int r = 0; r < 4; ++r) ps[r] += __shfl_xor(ps[r], off);
#pragma unroll
    for (int r = 0; r < 4; ++r) lrow[r] += ps[r];
  }
  float rl[4];
#pragma unroll
  for (int r = 0; r < 4; ++r) rl[r] = 1.f / lrow[r];
  for (int jt = 0; jt < 1024; jt += 64) {
    f32x4 s[4] = {};
#pragma unroll
    for (int n = 0; n < 4; ++n) {
      short8 bk[2];
#pragma unroll
      for (int kk = 0; kk < 2; ++kk)
        bk[kk] = *(const short8*)(v3h + (size_t)(jt + n * 16 + cq) * 64 + kk * 32 + rq * 8);
#pragma unroll
      for (int kk = 0; kk < 2; ++kk)
        s[n] = __builtin_amdgcn_mfma_f32_16x16x32_bf16(a_w[kk], bk[kk], s[n], 0, 0, 0);
    }
    float colsum[4] = {0.f, 0.f, 0.f, 0.f};
#pragma unroll
    for (int n = 0; n < 4; ++n)
#pragma unroll
      for (int r = 0; r < 4; ++r)
        colsum[n] += __expf(s[n][r] - mrow[r]) * rl[r];
#pragma unroll
    for (int n = 0; n < 4; ++n) {
      colsum[n] += __shfl_xor(colsum[n], 16);
      colsum[n] += __shfl_xor(colsum[n], 32);
    }
    if (lane < 16) {
#pragma unroll
      for (int n = 0; n < 4; ++n) cbuf[wv][jt + n * 16 + lane] += colsum[n];
    }
  }
  __syncthreads();
  for (int j = tid; j < 1024; j += 256)
    atomicAdd(&cross[(size_t)bh * 1024 + j], cbuf[0][j] + cbuf[1][j] + cbuf[2][j] + cbuf[3][j]);
}

// ---------------- fused self-attention, LDS-staged K/V, double-buffered ----------------
__global__ __launch_bounds__(256) void attn_kernel(const unsigned short* __restrict__ v1,
                                                   const unsigned short* __restrict__ v2,
                                                   const unsigned short* __restrict__ v4t,
                                                   const float* __restrict__ cross,
                                                   unsigned short* __restrict__ ctx) {
  __shared__ unsigned short Kt[2][64][64];
  __shared__ unsigned short Vt[2][64][64];
  __shared__ unsigned short Pbuf[4][16][64];
  const int bid = ((blockIdx.x & 7) << 7) | (blockIdx.x >> 3);  // bijective, 1024 % 8 == 0
  const int bh = bid >> 4, ib = bid & 15;
  const int b = bh >> 4, h = bh & 15;
  const int tid = threadIdx.x, lane = tid & 63, wv = tid >> 6;
  const int rq = lane >> 4, cq = lane & 15;
  const unsigned short* v1h = v1 + (size_t)bh * 1024 * 64;
  const unsigned short* v2h = v2 + (size_t)bh * 1024 * 64;
  const unsigned short* v4h = v4t + (size_t)bh * 64 * 1024;
  const float* ch = cross + (size_t)bh * 1024;
  const int i0 = ib * 64 + wv * 16;
  const int sr = lane >> 3;
  const int sc = ((lane & 7) ^ sr) * 8;
  short8 b_q[2];
#pragma unroll
  for (int kk = 0; kk < 2; ++kk)
    b_q[kk] = *(const short8*)(v1h + (size_t)(i0 + cq) * 64 + kk * 32 + rq * 8);
  float m = -3e38f, lsum = 0.f;
  f32x4 o[4] = {};

#pragma unroll
  for (int p = 0; p < 2; ++p) {
    int r = wv * 8 + p * 32 + sr;
    gload_lds16(v2h + (size_t)r * 64 + sc, &Kt[0][wv * 8 + p * 32][0]);
    gload_lds16(v4h + (size_t)r * 1024 + sc, &Vt[0][wv * 8 + p * 32][0]);
  }
  __syncthreads();

  for (int t = 0; t < 16; ++t) {
    const int cur = t & 1;
    const int jt = t * 64;
    if (t < 15) {
#pragma unroll
      for (int p = 0; p < 2; ++p) {
        int r = wv * 8 + p * 32 + sr;
        gload_lds16(v2h + (size_t)(jt + 64 + r) * 64 + sc, &Kt[cur ^ 1][wv * 8 + p * 32][0]);
        gload_lds16(v4h + (size_t)r * 1024 + jt + 64 + sc, &Vt[cur ^ 1][wv * 8 + p * 32][0]);
      }
    }
    f32x4 s[4] = {};
#pragma unroll
    for (int mp = 0; mp < 4; ++mp) {
      const int row = mp * 16 + cq;
      const char* base = (const char*)&Kt[cur][row][0];
#pragma unroll
      for (int kk = 0; kk < 2; ++kk) {
        short8 ak = *(const short8*)(base + ((((kk << 2) | rq) ^ (cq & 7)) << 4));
        s[mp] = __builtin_amdgcn_mfma_f32_16x16x32_bf16(ak, b_q[kk], s[mp], 0, 0, 0);
      }
    }
#pragma unroll
    for (int mp = 0; mp < 4; ++mp) {
      float4 cj = *(const float4*)(ch + jt + mp * 16 + rq * 4);
      s[mp][0] += cj.x; s[mp][1] += cj.y; s[mp][2] += cj.z; s[mp][3] += cj.w;
    }
    float tm = s[0][0];
#pragma unroll
    for (int mp = 0; mp < 4; ++mp)
#pragma unroll
      for (int r = 0; r < 4; ++r) tm = fmaxf(tm, s[mp][r]);
    tm = fmaxf(tm, __shfl_xor(tm, 16));
    tm = fmaxf(tm, __shfl_xor(tm, 32));
    float mn = fmaxf(m, tm);
    float alpha = __expf(m - mn);
    m = mn;
    float ps = 0.f;
#pragma unroll
    for (int mp = 0; mp < 4; ++mp)
#pragma unroll
      for (int r = 0; r < 4; ++r) {
        float p = __expf(s[mp][r] - mn);
        s[mp][r] = p;
        ps += p;
      }
    ps += __shfl_xor(ps, 16);
    ps += __shfl_xor(ps, 32);
    lsum = lsum * alpha + ps;
    {
      char* pb = (char*)&Pbuf[wv][cq][0];
      const int sw = (cq & 7) << 4;
#pragma unroll
      for (int mp = 0; mp < 4; ++mp) {
        ushort4 pw;
        pw.x = f2bf(s[mp][0]); pw.y = f2bf(s[mp][1]);
        pw.z = f2bf(s[mp][2]); pw.w = f2bf(s[mp][3]);
        *(ushort4*)(pb + ((mp * 32 + rq * 8) ^ sw)) = pw;
      }
    }
    short8 a_p[2];
    {
      const char* pb = (const char*)&Pbuf[wv][cq][0];
      const int sw = (cq & 7) << 4;
#pragma unroll
      for (int kk = 0; kk < 2; ++kk)
        a_p[kk] = *(const short8*)(pb + ((kk * 64 + rq * 16) ^ sw));
    }
    float al[4];
#pragma unroll
    for (int r = 0; r < 4; ++r) al[r] = __shfl(alpha, rq * 4 + r);
#pragma unroll
    for (int n = 0; n < 4; ++n)
#pragma unroll
      for (int r = 0; r < 4; ++r) o[n][r] *= al[r];
#pragma unroll
    for (int n = 0; n < 4; ++n) {
      const int row = n * 16 + cq;
      const char* base = (const char*)&Vt[cur][row][0];
#pragma unroll
      for (int kk = 0; kk < 2; ++kk) {
        short8 bv = *(const short8*)(base + ((((kk << 2) | rq) ^ (cq & 7)) << 4));
        o[n] = __builtin_amdgcn_mfma_f32_16x16x32_bf16(a_p[kk], bv, o[n], 0, 0, 0);
      }
    }
    __syncthreads();
  }
  float li[4];
#pragma unroll
  for (int r = 0; r < 4; ++r) li[r] = __shfl(lsum, rq * 4 + r);
#pragma unroll
  for (int n = 0; n < 4; ++n)
#pragma unroll
    for (int r = 0; r < 4; ++r) {
      float val = o[n][r] / li[r];
      int row = i0 + rq * 4 + r;
      int col = h * 64 + n * 16 + cq;
      ctx[((size_t)b * 1024 + row) * 1024 + col] = f2bf(val);
    }
}

extern "C" void kernel_launch(void* const* d_in, const int* in_sizes, int n_in,
                              void* d_out, int out_size, void* d_ws, size_t ws_size,
                              hipStream_t stream) {
  const int bs = in_sizes[0] / (128 * 1024);  // = 4
  char* w = (char*)d_ws;
  size_t off = 0;
  auto alloc = [&](size_t bytes) -> void* {
    void* p = w + off;
    off += (bytes + 255) & ~(size_t)255;
    return p;
  };
  unsigned short* wfeat_b = (unsigned short*)alloc((size_t)bs * 128 * 1024 * 2);
  unsigned short* vfeat_b = (unsigned short*)alloc((size_t)bs * 1024 * 1024 * 2);
  unsigned short* Ww1b = (unsigned short*)alloc((size_t)1024 * 1024 * 2);
  // Wv1..Wv4 contiguous (each 2MB, 256-aligned) -> one [4096][1024] matrix
  unsigned short* Wv1b = (unsigned short*)alloc((size_t)1024 * 1024 * 2);
  unsigned short* Wv2b = (unsigned short*)alloc((size_t)1024 * 1024 * 2);
  unsigned short* Wv3b = (unsigned short*)alloc((size_t)1024 * 1024 * 2);
  unsigned short* Wv4b = (unsigned short*)alloc((size_t)1024 * 1024 * 2);
  unsigned short* Woutb = (unsigned short*)alloc((size_t)1024 * 1024 * 2);
  unsigned short* w1b = (unsigned short*)alloc((size_t)bs * 16 * 128 * 64 * 2);
  unsigned short* v1b = (unsigned short*)alloc((size_t)bs * 16 * 1024 * 64 * 2);
  unsigned short* v2b = (unsigned short*)alloc((size_t)bs * 16 * 1024 * 64 * 2);
  unsigned short* v3b = (unsigned short*)alloc((size_t)bs * 16 * 1024 * 64 * 2);
  unsigned short* v4tb = (unsigned short*)alloc((size_t)bs * 16 * 64 * 1024 * 2);
  unsigned short* ctxb = (unsigned short*)alloc((size_t)bs * 1024 * 1024 * 2);
  float* crossb = (float*)alloc((size_t)bs * 16 * 1024 * 4);
  float* biascat = (float*)alloc((size_t)4096 * 4);

  auto cvt = [&](const void* src, unsigned short* dst, int n) {
    cvt_f2b<<<(n / 4 + 255) / 256, 256, 0, stream>>>((const float*)src, dst, n);
  };
  cvt(d_in[0], wfeat_b, bs * 128 * 1024);
  cvt(d_in[1], vfeat_b, bs * 1024 * 1024);
  cvt(d_in[2], Ww1b, 1024 * 1024);
  cvt(d_in[4], Wv1b, 1024 * 1024);
  cvt(d_in[6], Wv2b, 1024 * 1024);
  cvt(d_in[8], Wv3b, 1024 * 1024);
  cvt(d_in[10], Wv4b, 1024 * 1024);
  cvt(d_in[12], Woutb, 1024 * 1024);
  gather_bias<<<16, 256, 0, stream>>>((const float*)d_in[5], (const float*)d_in[7],
                                      (const float*)d_in[9], (const float*)d_in[11], biascat);
  zero_f32<<<64, 256, 0, stream>>>(crossb, bs * 16 * 1024 / 4);

  // w1 projection: M=512, 128^2 tiles -> grid (4,8)
  gemm_pipe<0, 128, 128, 2, 2><<<dim3(4, 8), 256, 0, stream>>>(
      wfeat_b, Ww1b, (const float*)d_in[3], w1b, nullptr, nullptr, nullptr, 7);
  // fused v1..v4 projection: M=4096, N=4096, 256^2 tiles -> grid (16,16), 512 thr
  gemm_pipe<3, 256, 256, 2, 4><<<dim3(16, 16), 512, 0, stream>>>(
      vfeat_b, Wv1b, biascat, v1b, v2b, v3b, v4tb, 10);
  // cross bias
  cross_kernel<<<bs * 16 * 2, 256, 0, stream>>>(w1b, v3b, crossb);
  // fused attention
  attn_kernel<<<bs * 16 * 16, 256, 0, stream>>>(v1b, v2b, v4tb, crossb, ctxb);
  // output projection: M=4096, N=1024, 128^2 tiles -> grid (32,8)
  gemm_pipe<2, 128, 128, 2, 2><<<dim3(32, 8), 256, 0, stream>>>(
      ctxb, Woutb, (const float*)d_in[13], (float*)d_out, nullptr, nullptr, nullptr, 0);
}

// Round 12
// 277.784 us; speedup vs baseline: 1.6874x; 1.1099x over previous
//
#include <hip/hip_runtime.h>

typedef __attribute__((ext_vector_type(8))) short short8;
typedef __attribute__((ext_vector_type(4))) float f32x4;

__device__ __forceinline__ unsigned short f2bf(float f) {
  unsigned int x = __float_as_uint(f);
  x += 0x7fffu + ((x >> 16) & 1u);
  return (unsigned short)(x >> 16);
}

__device__ __forceinline__ void gload_lds16(const void* g, void* l) {
  __builtin_amdgcn_global_load_lds((const __attribute__((address_space(1))) unsigned int*)g,
                                   (__attribute__((address_space(3))) unsigned int*)l, 16, 0, 0);
}

// ---------------- fused f32 -> bf16 conversion for all 8 tensors ----------------
struct CvtArgs {
  const float* src[8];
  unsigned short* dst[8];
  int cum4[9];  // prefix sums in float4 units
};
__global__ void cvt_all(CvtArgs a, int total4) {
  int g = blockIdx.x * 256 + threadIdx.x;
  if (g >= total4) return;
  int s = 0;
#pragma unroll
  for (int k = 1; k < 8; ++k) s += (g >= a.cum4[k]);
  int off = g - a.cum4[s];
  float4 v = *(const float4*)(a.src[s] + (size_t)off * 4);
  ushort4 o;
  o.x = f2bf(v.x); o.y = f2bf(v.y); o.z = f2bf(v.z); o.w = f2bf(v.w);
  *(ushort4*)(a.dst[s] + (size_t)off * 4) = o;
}

__global__ void gather_bias(const float* __restrict__ b0, const float* __restrict__ b1,
                            const float* __restrict__ b2, const float* __restrict__ b3,
                            float* __restrict__ out) {
  int i = blockIdx.x * 256 + threadIdx.x;  // 4096 total
  const float* src = (i < 1024) ? b0 : (i < 2048) ? b1 : (i < 3072) ? b2 : b3;
  out[i] = src[i & 1023];
}

__global__ void zero_f32(float* __restrict__ p, int n4) {
  int i = blockIdx.x * 256 + threadIdx.x;
  if (i < n4) *(float4*)(p + i * 4) = float4{0.f, 0.f, 0.f, 0.f};
}

// ======== Pipelined GEMM: Y[M x N] = X[M x 1024] @ W^T + bias ========
// Double-buffered K-tiles (BK=64), raw s_barrier + counted vmcnt(AI+BI), XOR-swizzled
// LDS, minimal ds_reads (B-frags hoisted once/tile, A-frags once/M-half).
// R11 lesson: 256^2/1-block-per-CU exposed ~30us of lockstep barrier stalls (all pipes
// <20%). Fix = cross-block TLP: 128^2 tiles, 64KB LDS -> 2 resident blocks/CU whose
// stalls overlap (m114 mechanism; how m97 hit 874 TF despite full drains).
// MODE 0: bf16 head layout [b][16][Nn][64]; MODE 2: f32 [M][1024];
// MODE 3: fused v-proj N=4096: slabs 0-2 head layout to o0..o2, slab 3 transposed to o3.
template<int MODE, int BM, int BN, int WM, int WN>
__global__ __launch_bounds__(WM * WN * 64, 2) void gemm_pipe(
    const unsigned short* __restrict__ X, const unsigned short* __restrict__ Wt,
    const float* __restrict__ bias, void* __restrict__ o0, void* __restrict__ o1,
    void* __restrict__ o2, void* __restrict__ o3, int nnShift) {
  constexpr int T = WM * WN * 64;
  constexpr int WAVES = WM * WN;
  constexpr int MR = BM / WM / 16;   // M frags per wave
  constexpr int NR = BN / WN / 16;   // N frags per wave
  constexpr int MH = (MR > 1) ? MR / 2 : 1;
  constexpr int MHALVES = MR / MH;
  constexpr int AI = BM * 8 / T;     // gload insts/thread for A tile
  constexpr int BI = BN * 8 / T;
  constexpr int NT = 1024 / 64;      // 16 K-tiles

  __shared__ unsigned short As[2][BM][64];
  __shared__ unsigned short Bs[2][BN][64];

  const int tid = threadIdx.x, lane = tid & 63, wv = tid >> 6;
  const int wm = wv % WM, wn = wv / WM;
  const int wMb = wm * (BM / WM), wNb = wn * (BN / WN);
  const int rowbase = blockIdx.x * BM, colbase = blockIdx.y * BN;
  const int rq = lane >> 4, cq = lane & 15;

  f32x4 acc[MR][NR] = {};

  // stage K-tile kt into dbuf slot s: linear LDS dest, source chunk pre-swizzled
  auto stage = [&](int s, int kt) {
#pragma unroll
    for (int j = 0; j < AI; ++j) {
      int cb = (j * WAVES + wv) * 64;          // wave-uniform chunk base
      int row = (cb + lane) >> 3;
      int srcc = (lane & 7) ^ (row & 7);
      gload_lds16(X + (size_t)(rowbase + row) * 1024 + kt * 64 + srcc * 8,
                  &As[s][cb >> 3][0]);
    }
#pragma unroll
    for (int j = 0; j < BI; ++j) {
      int cb = (j * WAVES + wv) * 64;
      int row = (cb + lane) >> 3;
      int srcc = (lane & 7) ^ (row & 7);
      gload_lds16(Wt + (size_t)(colbase + row) * 1024 + kt * 64 + srcc * 8,
                  &Bs[s][cb >> 3][0]);
    }
  };

  auto ktile = [&](int t, bool last) {
    if (last) {
      asm volatile("s_waitcnt vmcnt(0)" ::: "memory");
    } else {
      if constexpr (AI + BI == 8)      asm volatile("s_waitcnt vmcnt(8)" ::: "memory");
      else if constexpr (AI + BI == 6) asm volatile("s_waitcnt vmcnt(6)" ::: "memory");
      else                             asm volatile("s_waitcnt vmcnt(0)" ::: "memory");
    }
    __builtin_amdgcn_s_barrier();
    asm volatile("" ::: "memory");
    const int s = t & 1;
    // hoist ALL B-fragments once per K-tile (NR*2 reads)
    short8 bf[NR][2];
#pragma unroll
    for (int jf = 0; jf < NR; ++jf)
#pragma unroll
      for (int kk = 0; kk < 2; ++kk) {
        int row = wNb + jf * 16 + cq;
        int pc = (kk * 4 + rq) ^ (cq & 7);
        bf[jf][kk] = *(const short8*)(&Bs[s][row][pc * 8]);
      }
    // M-halves: A-fragments read once each
#pragma unroll
    for (int mh = 0; mh < MHALVES; ++mh) {
      short8 af[MH][2];
#pragma unroll
      for (int i = 0; i < MH; ++i)
#pragma unroll
        for (int kk = 0; kk < 2; ++kk) {
          int row = wMb + (mh * MH + i) * 16 + cq;
          int pc = (kk * 4 + rq) ^ (cq & 7);
          af[i][kk] = *(const short8*)(&As[s][row][pc * 8]);
        }
      __builtin_amdgcn_s_setprio(1);
#pragma unroll
      for (int i = 0; i < MH; ++i)
#pragma unroll
        for (int jf = 0; jf < NR; ++jf)
#pragma unroll
          for (int kk = 0; kk < 2; ++kk)
            acc[mh * MH + i][jf] = __builtin_amdgcn_mfma_f32_16x16x32_bf16(
                af[i][kk], bf[jf][kk], acc[mh * MH + i][jf], 0, 0, 0);
      __builtin_amdgcn_s_setprio(0);
    }
    asm volatile("" ::: "memory");
    __builtin_amdgcn_s_barrier();
    asm volatile("" ::: "memory");
    if (t + 2 < NT) stage(s, t + 2);  // S[s] free after end-of-tile barrier
  };

  // prologue: stage tiles 0 and 1 (2*(AI+BI) loads/thread outstanding)
  stage(0, 0);
  stage(1, 1);
  for (int t = 0; t < NT - 1; ++t) ktile(t, false);
  ktile(NT - 1, true);

  // epilogue
#pragma unroll
  for (int m = 0; m < MR; ++m)
#pragma unroll
    for (int n = 0; n < NR; ++n)
#pragma unroll
      for (int r = 0; r < 4; ++r) {
        int grow = rowbase + wMb + m * 16 + rq * 4 + r;
        int gcol = colbase + wNb + n * 16 + cq;
        float val = acc[m][n][r] + bias[gcol];
        if (MODE == 2) {
          ((float*)o0)[(size_t)grow * 1024 + gcol] = val;
        } else if (MODE == 0) {
          int bb = grow >> nnShift;
          int nr = grow & ((1 << nnShift) - 1);
          int hh = gcol >> 6, dd = gcol & 63;
          ((unsigned short*)o0)[((((size_t)bb * 16 + hh) << nnShift) + nr) * 64 + dd] = f2bf(val);
        } else {  // MODE 3
          int which = gcol >> 10;  // uniform per block (BN=128 divides 1024)
          int lcol = gcol & 1023;
          int bb = grow >> 10, nr = grow & 1023;
          int hh = lcol >> 6, dd = lcol & 63;
          void* op = (which == 0) ? o0 : (which == 1) ? o1 : (which == 2) ? o2 : o3;
          if (which < 3)
            ((unsigned short*)op)[((((size_t)bb * 16 + hh) << 10) + nr) * 64 + dd] = f2bf(val);
          else
            ((unsigned short*)op)[(((size_t)bb * 16 + hh) * 64 + dd) * 1024 + nr] = f2bf(val);
        }
      }
}

// ---------------- cross path: cross[b,h,j] += sum_{w in half} softmax_j(w1[w] . v3[j]) ----------------
__global__ __launch_bounds__(256) void cross_kernel(const unsigned short* __restrict__ w1,
                                                    const unsigned short* __restrict__ v3,
                                                    float* __restrict__ cross) {
  __shared__ float cbuf[4][1024];
  const int tid = threadIdx.x, lane = tid & 63, wv = tid >> 6;
  const int rq = lane >> 4, cq = lane & 15;
  for (int i = tid; i < 4096; i += 256) ((float*)cbuf)[i] = 0.f;
  __syncthreads();
  const int bh = blockIdx.x >> 1, half = blockIdx.x & 1;
  const unsigned short* w1h = w1 + (size_t)bh * 128 * 64;
  const unsigned short* v3h = v3 + (size_t)bh * 1024 * 64;
  const int w0 = half * 64 + wv * 16;
  short8 a_w[2];
#pragma unroll
  for (int kk = 0; kk < 2; ++kk)
    a_w[kk] = *(const short8*)(w1h + (size_t)(w0 + cq) * 64 + kk * 32 + rq * 8);
  float mrow[4], lrow[4];
#pragma unroll
  for (int r = 0; r < 4; ++r) { mrow[r] = -3e38f; lrow[r] = 0.f; }
  for (int jt = 0; jt < 1024; jt += 64) {
    f32x4 s[4] = {};
#pragma unroll
    for (int n = 0; n < 4; ++n) {
      short8 bk[2];
#pragma unroll
      for (int kk = 0; kk < 2; ++kk)
        bk[kk] = *(const short8*)(v3h + (size_t)(jt + n * 16 + cq) * 64 + kk * 32 + rq * 8);
#pragma unroll
      for (int kk = 0; kk < 2; ++kk)
        s[n] = __builtin_amdgcn_mfma_f32_16x16x32_bf16(a_w[kk], bk[kk], s[n], 0, 0, 0);
    }
    float tm[4], ps[4];
#pragma unroll
    for (int r = 0; r < 4; ++r)
      tm[r] = fmaxf(fmaxf(s[0][r], s[1][r]), fmaxf(s[2][r], s[3][r]));
    for (int off = 1; off < 16; off <<= 1)
#pragma unroll
      for (int r = 0; r < 4; ++r) tm[r] = fmaxf(tm[r], __shfl_xor(tm[r], off));
#pragma unroll
    for (int r = 0; r < 4; ++r) {
      float mn = fmaxf(mrow[r], tm[r]);
      float al = __expf(mrow[r] - mn);
      mrow[r] = mn;
      float p = 0.f;
#pragma unroll
      for (int n = 0; n < 4; ++n) p += __expf(s[n][r] - mn);
      ps[r] = p;
      lrow[r] *= al;
    }
    for (int off = 1; off < 16; off <<= 1)
#pragma unroll
      for (int r = 0; r < 4; ++r) ps[r] += __shfl_xor(ps[r], off);
#pragma unroll
    for (int r = 0; r < 4; ++r) lrow[r] += ps[r];
  }
  float rl[4];
#pragma unroll
  for (int r = 0; r < 4; ++r) rl[r] = 1.f / lrow[r];
  for (int jt = 0; jt < 1024; jt += 64) {
    f32x4 s[4] = {};
#pragma unroll
    for (int n = 0; n < 4; ++n) {
      short8 bk[2];
#pragma unroll
      for (int kk = 0; kk < 2; ++kk)
        bk[kk] = *(const short8*)(v3h + (size_t)(jt + n * 16 + cq) * 64 + kk * 32 + rq * 8);
#pragma unroll
      for (int kk = 0; kk < 2; ++kk)
        s[n] = __builtin_amdgcn_mfma_f32_16x16x32_bf16(a_w[kk], bk[kk], s[n], 0, 0, 0);
    }
    float colsum[4] = {0.f, 0.f, 0.f, 0.f};
#pragma unroll
    for (int n = 0; n < 4; ++n)
#pragma unroll
      for (int r = 0; r < 4; ++r)
        colsum[n] += __expf(s[n][r] - mrow[r]) * rl[r];
#pragma unroll
    for (int n = 0; n < 4; ++n) {
      colsum[n] += __shfl_xor(colsum[n], 16);
      colsum[n] += __shfl_xor(colsum[n], 32);
    }
    if (lane < 16) {
#pragma unroll
      for (int n = 0; n < 4; ++n) cbuf[wv][jt + n * 16 + lane] += colsum[n];
    }
  }
  __syncthreads();
  for (int j = tid; j < 1024; j += 256)
    atomicAdd(&cross[(size_t)bh * 1024 + j], cbuf[0][j] + cbuf[1][j] + cbuf[2][j] + cbuf[3][j]);
}

// ---------------- fused self-attention, LDS-staged K/V, double-buffered ----------------
__global__ __launch_bounds__(256) void attn_kernel(const unsigned short* __restrict__ v1,
                                                   const unsigned short* __restrict__ v2,
                                                   const unsigned short* __restrict__ v4t,
                                                   const float* __restrict__ cross,
                                                   unsigned short* __restrict__ ctx) {
  __shared__ unsigned short Kt[2][64][64];
  __shared__ unsigned short Vt[2][64][64];
  __shared__ unsigned short Pbuf[4][16][64];
  const int bid = ((blockIdx.x & 7) << 7) | (blockIdx.x >> 3);  // bijective, 1024 % 8 == 0
  const int bh = bid >> 4, ib = bid & 15;
  const int b = bh >> 4, h = bh & 15;
  const int tid = threadIdx.x, lane = tid & 63, wv = tid >> 6;
  const int rq = lane >> 4, cq = lane & 15;
  const unsigned short* v1h = v1 + (size_t)bh * 1024 * 64;
  const unsigned short* v2h = v2 + (size_t)bh * 1024 * 64;
  const unsigned short* v4h = v4t + (size_t)bh * 64 * 1024;
  const float* ch = cross + (size_t)bh * 1024;
  const int i0 = ib * 64 + wv * 16;
  const int sr = lane >> 3;
  const int sc = ((lane & 7) ^ sr) * 8;
  short8 b_q[2];
#pragma unroll
  for (int kk = 0; kk < 2; ++kk)
    b_q[kk] = *(const short8*)(v1h + (size_t)(i0 + cq) * 64 + kk * 32 + rq * 8);
  float m = -3e38f, lsum = 0.f;
  f32x4 o[4] = {};

#pragma unroll
  for (int p = 0; p < 2; ++p) {
    int r = wv * 8 + p * 32 + sr;
    gload_lds16(v2h + (size_t)r * 64 + sc, &Kt[0][wv * 8 + p * 32][0]);
    gload_lds16(v4h + (size_t)r * 1024 + sc, &Vt[0][wv * 8 + p * 32][0]);
  }
  __syncthreads();

  for (int t = 0; t < 16; ++t) {
    const int cur = t & 1;
    const int jt = t * 64;
    if (t < 15) {
#pragma unroll
      for (int p = 0; p < 2; ++p) {
        int r = wv * 8 + p * 32 + sr;
        gload_lds16(v2h + (size_t)(jt + 64 + r) * 64 + sc, &Kt[cur ^ 1][wv * 8 + p * 32][0]);
        gload_lds16(v4h + (size_t)r * 1024 + jt + 64 + sc, &Vt[cur ^ 1][wv * 8 + p * 32][0]);
      }
    }
    f32x4 s[4] = {};
#pragma unroll
    for (int mp = 0; mp < 4; ++mp) {
      const int row = mp * 16 + cq;
      const char* base = (const char*)&Kt[cur][row][0];
#pragma unroll
      for (int kk = 0; kk < 2; ++kk) {
        short8 ak = *(const short8*)(base + ((((kk << 2) | rq) ^ (cq & 7)) << 4));
        s[mp] = __builtin_amdgcn_mfma_f32_16x16x32_bf16(ak, b_q[kk], s[mp], 0, 0, 0);
      }
    }
#pragma unroll
    for (int mp = 0; mp < 4; ++mp) {
      float4 cj = *(const float4*)(ch + jt + mp * 16 + rq * 4);
      s[mp][0] += cj.x; s[mp][1] += cj.y; s[mp][2] += cj.z; s[mp][3] += cj.w;
    }
    float tm = s[0][0];
#pragma unroll
    for (int mp = 0; mp < 4; ++mp)
#pragma unroll
      for (int r = 0; r < 4; ++r) tm = fmaxf(tm, s[mp][r]);
    tm = fmaxf(tm, __shfl_xor(tm, 16));
    tm = fmaxf(tm, __shfl_xor(tm, 32));
    float mn = fmaxf(m, tm);
    float alpha = __expf(m - mn);
    m = mn;
    float ps = 0.f;
#pragma unroll
    for (int mp = 0; mp < 4; ++mp)
#pragma unroll
      for (int r = 0; r < 4; ++r) {
        float p = __expf(s[mp][r] - mn);
        s[mp][r] = p;
        ps += p;
      }
    ps += __shfl_xor(ps, 16);
    ps += __shfl_xor(ps, 32);
    lsum = lsum * alpha + ps;
    {
      char* pb = (char*)&Pbuf[wv][cq][0];
      const int sw = (cq & 7) << 4;
#pragma unroll
      for (int mp = 0; mp < 4; ++mp) {
        ushort4 pw;
        pw.x = f2bf(s[mp][0]); pw.y = f2bf(s[mp][1]);
        pw.z = f2bf(s[mp][2]); pw.w = f2bf(s[mp][3]);
        *(ushort4*)(pb + ((mp * 32 + rq * 8) ^ sw)) = pw;
      }
    }
    short8 a_p[2];
    {
      const char* pb = (const char*)&Pbuf[wv][cq][0];
      const int sw = (cq & 7) << 4;
#pragma unroll
      for (int kk = 0; kk < 2; ++kk)
        a_p[kk] = *(const short8*)(pb + ((kk * 64 + rq * 16) ^ sw));
    }
    float al[4];
#pragma unroll
    for (int r = 0; r < 4; ++r) al[r] = __shfl(alpha, rq * 4 + r);
#pragma unroll
    for (int n = 0; n < 4; ++n)
#pragma unroll
      for (int r = 0; r < 4; ++r) o[n][r] *= al[r];
#pragma unroll
    for (int n = 0; n < 4; ++n) {
      const int row = n * 16 + cq;
      const char* base = (const char*)&Vt[cur][row][0];
#pragma unroll
      for (int kk = 0; kk < 2; ++kk) {
        short8 bv = *(const short8*)(base + ((((kk << 2) | rq) ^ (cq & 7)) << 4));
        o[n] = __builtin_amdgcn_mfma_f32_16x16x32_bf16(a_p[kk], bv, o[n], 0, 0, 0);
      }
    }
    __syncthreads();
  }
  float li[4];
#pragma unroll
  for (int r = 0; r < 4; ++r) li[r] = __shfl(lsum, rq * 4 + r);
#pragma unroll
  for (int n = 0; n < 4; ++n)
#pragma unroll
    for (int r = 0; r < 4; ++r) {
      float val = o[n][r] / li[r];
      int row = i0 + rq * 4 + r;
      int col = h * 64 + n * 16 + cq;
      ctx[((size_t)b * 1024 + row) * 1024 + col] = f2bf(val);
    }
}

extern "C" void kernel_launch(void* const* d_in, const int* in_sizes, int n_in,
                              void* d_out, int out_size, void* d_ws, size_t ws_size,
                              hipStream_t stream) {
  const int bs = in_sizes[0] / (128 * 1024);  // = 4
  char* w = (char*)d_ws;
  size_t off = 0;
  auto alloc = [&](size_t bytes) -> void* {
    void* p = w + off;
    off += (bytes + 255) & ~(size_t)255;
    return p;
  };
  unsigned short* wfeat_b = (unsigned short*)alloc((size_t)bs * 128 * 1024 * 2);
  unsigned short* vfeat_b = (unsigned short*)alloc((size_t)bs * 1024 * 1024 * 2);
  unsigned short* Ww1b = (unsigned short*)alloc((size_t)1024 * 1024 * 2);
  // Wv1..Wv4 contiguous (each 2MB, 256-aligned) -> one [4096][1024] matrix
  unsigned short* Wv1b = (unsigned short*)alloc((size_t)1024 * 1024 * 2);
  unsigned short* Wv2b = (unsigned short*)alloc((size_t)1024 * 1024 * 2);
  unsigned short* Wv3b = (unsigned short*)alloc((size_t)1024 * 1024 * 2);
  unsigned short* Wv4b = (unsigned short*)alloc((size_t)1024 * 1024 * 2);
  unsigned short* Woutb = (unsigned short*)alloc((size_t)1024 * 1024 * 2);
  unsigned short* w1b = (unsigned short*)alloc((size_t)bs * 16 * 128 * 64 * 2);
  unsigned short* v1b = (unsigned short*)alloc((size_t)bs * 16 * 1024 * 64 * 2);
  unsigned short* v2b = (unsigned short*)alloc((size_t)bs * 16 * 1024 * 64 * 2);
  unsigned short* v3b = (unsigned short*)alloc((size_t)bs * 16 * 1024 * 64 * 2);
  unsigned short* v4tb = (unsigned short*)alloc((size_t)bs * 16 * 64 * 1024 * 2);
  unsigned short* ctxb = (unsigned short*)alloc((size_t)bs * 1024 * 1024 * 2);
  float* crossb = (float*)alloc((size_t)bs * 16 * 1024 * 4);
  float* biascat = (float*)alloc((size_t)4096 * 4);

  // one fused conversion kernel for all 8 f32->bf16 tensors
  CvtArgs ca;
  const int srcIdx[8] = {0, 1, 2, 4, 6, 8, 10, 12};
  unsigned short* dsts[8] = {wfeat_b, vfeat_b, Ww1b, Wv1b, Wv2b, Wv3b, Wv4b, Woutb};
  int cum = 0;
  for (int k = 0; k < 8; ++k) {
    ca.src[k] = (const float*)d_in[srcIdx[k]];
    ca.dst[k] = dsts[k];
    ca.cum4[k] = cum;
    cum += in_sizes[srcIdx[k]] / 4;
  }
  ca.cum4[8] = cum;
  cvt_all<<<(cum + 255) / 256, 256, 0, stream>>>(ca, cum);
  gather_bias<<<16, 256, 0, stream>>>((const float*)d_in[5], (const float*)d_in[7],
                                      (const float*)d_in[9], (const float*)d_in[11], biascat);
  zero_f32<<<64, 256, 0, stream>>>(crossb, bs * 16 * 1024 / 4);

  // w1 projection: M=512, 128^2 tiles -> grid (4,8)
  gemm_pipe<0, 128, 128, 2, 2><<<dim3(4, 8), 256, 0, stream>>>(
      wfeat_b, Ww1b, (const float*)d_in[3], w1b, nullptr, nullptr, nullptr, 7);
  // fused v1..v4 projection: M=4096, N=4096, 128^2 tiles -> grid (32,32), 1024 blocks
  // (2 resident blocks/CU -> independent barrier domains overlap stalls)
  gemm_pipe<3, 128, 128, 2, 2><<<dim3(32, 32), 256, 0, stream>>>(
      vfeat_b, Wv1b, biascat, v1b, v2b, v3b, v4tb, 10);
  // cross bias
  cross_kernel<<<bs * 16 * 2, 256, 0, stream>>>(w1b, v3b, crossb);
  // fused attention
  attn_kernel<<<bs * 16 * 16, 256, 0, stream>>>(v1b, v2b, v4tb, crossb, ctxb);
  // output projection: M=4096, N=1024, 64x128 tiles -> grid (64,8) = 512 blocks (2/CU)
  gemm_pipe<2, 64, 128, 2, 2><<<dim3(64, 8), 256, 0, stream>>>(
      ctxb, Woutb, (const float*)d_in[13], (float*)d_out, nullptr, nullptr, nullptr, 0);
}